// Round 12
// baseline (1347.439 us; speedup 1.0000x reference)
//
#include <hip/hip_runtime.h>

#define EPS 1e-6f

typedef __attribute__((ext_vector_type(8))) short short8;
typedef __attribute__((ext_vector_type(8))) _Float16 half8;
typedef __attribute__((ext_vector_type(4))) float floatx4;
typedef __attribute__((ext_vector_type(2))) float floatx2;

struct ScanArgs {
    const float* xw[4];
    const float* whh[4];
    float* out[4];
    int flipOut[4];
    int writeAll;
    int outStride;
};

struct MfArgs {
    const unsigned short* X;        // [8192][Kaug] augmented bf16
    const unsigned short* W[4];     // [512][Kaug] augmented bf16
    const float* bias[4];
    float* out[4];                  // [4096][512] fp32
    int flip[4];
    int rowBase[4];
    int Kaug;
};

__device__ __forceinline__ float fsig(float x) { return 1.0f / (1.0f + __expf(-x)); }
__device__ __forceinline__ float tanh_fast(float x) {
    float e = __expf(2.f * x);
    return 1.f - 2.f / (e + 1.f);
}
__device__ __forceinline__ unsigned short f2bf(float x) {
    unsigned u = __float_as_uint(x);
    return (unsigned short)((u + 0x7fffu + ((u >> 16) & 1u)) >> 16);
}
__device__ __forceinline__ void split8_bf(const float* p, short8& hi, short8& lo) {
    #pragma unroll
    for (int e = 0; e < 8; ++e) {
        unsigned short h = f2bf(p[e]);
        float hf = __uint_as_float((unsigned)h << 16);
        hi[e] = (short)h;
        lo[e] = (short)f2bf(p[e] - hf);
    }
}
__device__ __forceinline__ void split8_f16(const float* p, half8& hi, half8& lo) {
    #pragma unroll
    for (int e = 0; e < 8; ++e) {
        _Float16 h = (_Float16)p[e];
        hi[e] = h;
        lo[e] = (_Float16)(p[e] - (float)h);
    }
}
__device__ __forceinline__ floatx2 pk_fma(floatx2 a, floatx2 b, floatx2 c) {
    floatx2 d;
    asm("v_pk_fma_f32 %0, %1, %2, %3" : "=v"(d) : "v"(a), "v"(b), "v"(c));
    return d;
}

// ---------------- word embedding gather -> split-bf16 Xaug directly ----------------
__global__ void k_embed_word(const int* __restrict__ idxA, const int* __restrict__ idxB,
                             const float* __restrict__ emb,
                             unsigned short* __restrict__ Xaug) {
    int row = blockIdx.x;              // 0..8191 (A rows 0..4095, B rows 4096..8191)
    const int* idx = (row < 4096) ? idxA : idxB;
    int r = row & 4095;
    size_t e = (size_t)idx[r];
    const float* src = emb + e * 300;
    unsigned short* d = Xaug + (size_t)row * 1152;
    for (int k = threadIdx.x; k < 384; k += blockDim.x) {
        float x = (k < 300) ? src[k] : 0.f;
        unsigned short hr = f2bf(x);
        float hif = __uint_as_float((unsigned)hr << 16);
        unsigned short lr2 = f2bf(x - hif);
        d[k]       = hr;
        d[384 + k] = lr2;
        d[768 + k] = hr;
    }
}

// ---------------- fp32 -> augmented split-bf16 (X: [hi|lo|hi], W: [hi|hi|lo]) ------------
__global__ void k_conv(const float* __restrict__ src, unsigned short* __restrict__ dst,
                       int K, int Ksec, int isW) {
    int row = blockIdx.x;
    const float* s = src + (size_t)row * K;
    unsigned short* d = dst + (size_t)row * (3 * Ksec);
    int o1 = (isW ? 2 : 1) * Ksec;   // where lo goes
    int o2 = (isW ? 1 : 2) * Ksec;   // where second hi goes
    for (int k = threadIdx.x; k < Ksec; k += blockDim.x) {
        float x = (k < K) ? s[k] : 0.f;
        unsigned short hr = f2bf(x);
        float hif = __uint_as_float((unsigned)hr << 16);
        unsigned short lr2 = f2bf(x - hif);
        d[k]      = hr;
        d[o1 + k] = lr2;
        d[o2 + k] = hr;
    }
}

// ---------------- char LSTM via MFMA: 32 seqs/block -> split-bf16 Xaug cols 300..363 -----
__global__ __launch_bounds__(256, 1)
void k_char_mfma(const int* __restrict__ cidxA, const int* __restrict__ cidxB,
                 const float* __restrict__ emb,
                 const unsigned short* __restrict__ WihA, const unsigned short* __restrict__ WhhA,
                 const float* __restrict__ bias,
                 unsigned short* __restrict__ Xaug) {
    __shared__ __align__(16) float xs[32][68];
    __shared__ __align__(16) float hs[32][68];
    int tid = threadIdx.x;
    int w = tid >> 6, l = tid & 63, lr = l & 15, lc = l >> 4;
    int j = w * 16 + lr;              // h-dim column this lane covers
    short8 wih[4][6], whh[4][6];
    #pragma unroll
    for (int g = 0; g < 4; ++g)
        #pragma unroll
        for (int kt = 0; kt < 6; ++kt) {
            wih[g][kt] = *(const short8*)&WihA[(size_t)(g*64 + j)*192 + kt*32 + lc*8];
            whh[g][kt] = *(const short8*)&WhhA[(size_t)(g*64 + j)*192 + kt*32 + lc*8];
        }
    float bg[4];
    #pragma unroll
    for (int g = 0; g < 4; ++g) bg[g] = bias[g*64 + j];
    int seq0 = blockIdx.x * 32;
    for (int m = tid; m < 32*68; m += 256) (&hs[0][0])[m] = 0.f;
    float cst[2][4] = {};
    float hlast[2][4];
    __syncthreads();
    for (int t = 0; t < 8; ++t) {
        {
            int s = tid >> 3, ch = tid & 7;
            int sq = seq0 + s;
            const int* ci = (sq < 4096) ? cidxA : cidxB;
            int e = ci[(sq & 4095)*8 + t];
            float4 v0 = *(const float4*)&emb[(size_t)e*64 + ch*8];
            float4 v1 = *(const float4*)&emb[(size_t)e*64 + ch*8 + 4];
            *(float4*)&xs[s][ch*8] = v0;
            *(float4*)&xs[s][ch*8 + 4] = v1;
        }
        short8 hhi[2][2], hlo[2][2];
        if (t > 0) {
            #pragma unroll
            for (int mt = 0; mt < 2; ++mt)
                #pragma unroll
                for (int kt = 0; kt < 2; ++kt) {
                    float tmp[8];
                    *(float4*)&tmp[0] = *(const float4*)&hs[mt*16 + lr][kt*32 + lc*8];
                    *(float4*)&tmp[4] = *(const float4*)&hs[mt*16 + lr][kt*32 + lc*8 + 4];
                    split8_bf(tmp, hhi[mt][kt], hlo[mt][kt]);
                }
        }
        __syncthreads();   // A: xs staged; hs reads done
        short8 xhi[2][2], xlo[2][2];
        #pragma unroll
        for (int mt = 0; mt < 2; ++mt)
            #pragma unroll
            for (int kt = 0; kt < 2; ++kt) {
                float tmp[8];
                *(float4*)&tmp[0] = *(const float4*)&xs[mt*16 + lr][kt*32 + lc*8];
                *(float4*)&tmp[4] = *(const float4*)&xs[mt*16 + lr][kt*32 + lc*8 + 4];
                split8_bf(tmp, xhi[mt][kt], xlo[mt][kt]);
            }
        #pragma unroll
        for (int mt = 0; mt < 2; ++mt)
            #pragma unroll
            for (int g = 0; g < 4; ++g) {
                floatx4 a = {bg[g], bg[g], bg[g], bg[g]};
                a = __builtin_amdgcn_mfma_f32_16x16x32_bf16(xhi[mt][0], wih[g][0], a, 0, 0, 0);
                a = __builtin_amdgcn_mfma_f32_16x16x32_bf16(xhi[mt][1], wih[g][1], a, 0, 0, 0);
                a = __builtin_amdgcn_mfma_f32_16x16x32_bf16(xlo[mt][0], wih[g][2], a, 0, 0, 0);
                a = __builtin_amdgcn_mfma_f32_16x16x32_bf16(xlo[mt][1], wih[g][3], a, 0, 0, 0);
                a = __builtin_amdgcn_mfma_f32_16x16x32_bf16(xhi[mt][0], wih[g][4], a, 0, 0, 0);
                a = __builtin_amdgcn_mfma_f32_16x16x32_bf16(xhi[mt][1], wih[g][5], a, 0, 0, 0);
                if (t > 0) {
                    a = __builtin_amdgcn_mfma_f32_16x16x32_bf16(hhi[mt][0], whh[g][0], a, 0, 0, 0);
                    a = __builtin_amdgcn_mfma_f32_16x16x32_bf16(hhi[mt][1], whh[g][1], a, 0, 0, 0);
                    a = __builtin_amdgcn_mfma_f32_16x16x32_bf16(hlo[mt][0], whh[g][2], a, 0, 0, 0);
                    a = __builtin_amdgcn_mfma_f32_16x16x32_bf16(hlo[mt][1], whh[g][3], a, 0, 0, 0);
                    a = __builtin_amdgcn_mfma_f32_16x16x32_bf16(hhi[mt][0], whh[g][4], a, 0, 0, 0);
                    a = __builtin_amdgcn_mfma_f32_16x16x32_bf16(hhi[mt][1], whh[g][5], a, 0, 0, 0);
                }
                if (g == 0) { hlast[mt][0] = a[0]; hlast[mt][1] = a[1]; hlast[mt][2] = a[2]; hlast[mt][3] = a[3]; }
                else if (g == 1) {
                    #pragma unroll
                    for (int i = 0; i < 4; ++i) cst[mt][i] = fsig(a[i]) * cst[mt][i];
                } else if (g == 2) {
                    #pragma unroll
                    for (int i = 0; i < 4; ++i) cst[mt][i] += fsig(hlast[mt][i]) * tanh_fast(a[i]);
                } else {
                    #pragma unroll
                    for (int i = 0; i < 4; ++i) {
                        float h = fsig(a[i]) * tanh_fast(cst[mt][i]);
                        hlast[mt][i] = h;
                        hs[mt*16 + lc*4 + i][j] = h;
                    }
                }
            }
        __syncthreads();   // B: hs writes visible; xs reads done
    }
    #pragma unroll
    for (int mt = 0; mt < 2; ++mt)
        #pragma unroll
        for (int i = 0; i < 4; ++i) {
            int s = mt*16 + lc*4 + i;
            int sq = seq0 + s;                     // global Xaug row
            unsigned short* d = Xaug + (size_t)sq * 1152;
            float h = hlast[mt][i];
            unsigned short hh = f2bf(h);
            float hf = __uint_as_float((unsigned)hh << 16);
            unsigned short hl = f2bf(h - hf);
            int k = 300 + j;
            d[k]       = hh;
            d[384 + k] = hl;
            d[768 + k] = hh;
        }
}

// ---------------- MFMA input-projection GEMM: out[row][n] = bias[n] + sum_k X[srow][k]*W[n][k]
__global__ __launch_bounds__(256, 2)
void k_xw_mfma(MfArgs a) {
    int scan = blockIdx.z;
    const unsigned short* X = a.X;
    const unsigned short* W = a.W[scan];
    const float* bias = a.bias[scan];
    float* out = a.out[scan];
    int flip = a.flip[scan];
    int rowBase = a.rowBase[scan];
    int Kaug = a.Kaug;
    int m0 = blockIdx.x * 128;
    int n0 = blockIdx.y * 128;
    __shared__ __align__(16) unsigned short As[128][40];
    __shared__ __align__(16) unsigned short Bs[128][40];
    int tid = threadIdx.x;
    int wv = tid >> 6, lane = tid & 63;
    int lr = lane & 15, lc = lane >> 4;

    floatx4 acc[2][8];
    #pragma unroll
    for (int f = 0; f < 2; ++f)
        #pragma unroll
        for (int g = 0; g < 8; ++g)
            acc[f][g] = (floatx4){0.f, 0.f, 0.f, 0.f};

    int r0 = m0 + (tid >> 2);
    int r1 = r0 + 64;
    int sr0 = rowBase + (flip ? ((r0 & ~63) | (63 - (r0 & 63))) : r0);
    int sr1 = rowBase + (flip ? ((r1 & ~63) | (63 - (r1 & 63))) : r1);
    size_t asrc0 = (size_t)sr0 * Kaug + (tid & 3) * 8;
    size_t asrc1 = (size_t)sr1 * Kaug + (tid & 3) * 8;
    size_t bsrc0 = (size_t)(n0 + (tid >> 2)) * Kaug + (tid & 3) * 8;
    size_t bsrc1 = (size_t)(n0 + (tid >> 2) + 64) * Kaug + (tid & 3) * 8;
    int swrow = tid >> 2, swcol = (tid & 3) * 8;

    for (int k0 = 0; k0 < Kaug; k0 += 32) {
        short8 a0 = *(const short8*)(X + asrc0 + k0);
        short8 a1 = *(const short8*)(X + asrc1 + k0);
        short8 b0 = *(const short8*)(W + bsrc0 + k0);
        short8 b1 = *(const short8*)(W + bsrc1 + k0);
        __syncthreads();
        *(short8*)&As[swrow][swcol]      = a0;
        *(short8*)&As[swrow + 64][swcol] = a1;
        *(short8*)&Bs[swrow][swcol]      = b0;
        *(short8*)&Bs[swrow + 64][swcol] = b1;
        __syncthreads();
        short8 af0 = *(const short8*)&As[wv*32 + lr][lc*8];
        short8 af1 = *(const short8*)&As[wv*32 + 16 + lr][lc*8];
        #pragma unroll
        for (int g = 0; g < 8; ++g) {
            short8 bf = *(const short8*)&Bs[g*16 + lr][lc*8];
            acc[0][g] = __builtin_amdgcn_mfma_f32_16x16x32_bf16(af0, bf, acc[0][g], 0, 0, 0);
            acc[1][g] = __builtin_amdgcn_mfma_f32_16x16x32_bf16(af1, bf, acc[1][g], 0, 0, 0);
        }
    }

    #pragma unroll
    for (int f = 0; f < 2; ++f) {
        int row = m0 + wv*32 + f*16 + lc*4;
        #pragma unroll
        for (int g = 0; g < 8; ++g) {
            int col = n0 + g*16 + lr;
            float bv = bias[col];
            #pragma unroll
            for (int i = 0; i < 4; ++i)
                out[(size_t)(row + i)*512 + col] = acc[f][g][i] + bv;
        }
    }
}

// ---------------- LSTM recurrence: 1024 threads, split-K, packed-fp32 FMA -----------------
// gates i,f weights staged in LDS (row-padded to 129 floats -> conflict-free);
// gates g,o weights stream from L2 each step (half the previous traffic).
__global__ __launch_bounds__(1024, 1)
void k_lstm_scan(ScanArgs a) {
    int b = blockIdx.x;
    int scan = blockIdx.y;
    int tid = threadIdx.x;
    int p = tid >> 9;                  // K-half 0/1
    int g = tid & 511;                 // gate row
    __shared__ __align__(16) float wlds[256*129];     // gates i,f: 132KB, stride 129
    __shared__ __align__(16) float h_lds[128];
    __shared__ float gpart[2][512];
    const float* W = a.whh[scan];
    // stage rows 0..255 (gates i,f) into LDS with +1-row padding
    for (int m = tid; m < 32768; m += 1024) {
        int r = m >> 7, cc = m & 127;
        wlds[r*129 + cc] = W[m];
    }
    const float* xw = a.xw[scan] + (size_t)b*64*512;
    float* outp = a.out[scan];
    int flip = a.flipOut[scan];
    int wAll = a.writeAll;
    float c = 0.f;
    if (tid < 128) h_lds[tid] = 0.f;
    __syncthreads();
    const float* hb = &h_lds[p*64];
    const float* wl = &wlds[(g & 255)*129 + p*64];            // LDS weights (g < 256)
    const float* wg = W + (size_t)g*128 + p*64;               // global weights (g >= 256)
    float xwc = (p == 0) ? xw[g] : 0.f;
    for (int t = 0; t < 64; ++t) {
        float xwn = 0.f;
        if (p == 0 && t < 63) xwn = xw[(size_t)(t+1)*512 + g];
        floatx2 a0 = {0.f,0.f}, a1 = {0.f,0.f}, a2 = {0.f,0.f}, a3 = {0.f,0.f};
        if (g < 256) {
            #pragma unroll
            for (int kk = 0; kk < 8; ++kk) {
                floatx4 u = *(const floatx4*)&hb[kk*8];
                floatx4 v = *(const floatx4*)&hb[kk*8 + 4];
                a0 = pk_fma(*(const floatx2*)&wl[kk*8 + 0], __builtin_shufflevector(u, u, 0, 1), a0);
                a1 = pk_fma(*(const floatx2*)&wl[kk*8 + 2], __builtin_shufflevector(u, u, 2, 3), a1);
                a2 = pk_fma(*(const floatx2*)&wl[kk*8 + 4], __builtin_shufflevector(v, v, 0, 1), a2);
                a3 = pk_fma(*(const floatx2*)&wl[kk*8 + 6], __builtin_shufflevector(v, v, 2, 3), a3);
            }
        } else {
            #pragma unroll
            for (int kk = 0; kk < 8; ++kk) {
                floatx4 u = *(const floatx4*)&hb[kk*8];
                floatx4 v = *(const floatx4*)&hb[kk*8 + 4];
                a0 = pk_fma(*(const floatx2*)&wg[kk*8 + 0], __builtin_shufflevector(u, u, 0, 1), a0);
                a1 = pk_fma(*(const floatx2*)&wg[kk*8 + 2], __builtin_shufflevector(u, u, 2, 3), a1);
                a2 = pk_fma(*(const floatx2*)&wg[kk*8 + 4], __builtin_shufflevector(v, v, 0, 1), a2);
                a3 = pk_fma(*(const floatx2*)&wg[kk*8 + 6], __builtin_shufflevector(v, v, 2, 3), a3);
            }
        }
        float s = ((a0.x + a0.y) + (a1.x + a1.y)) + ((a2.x + a2.y) + (a3.x + a3.y));
        gpart[p][g] = xwc + s;
        __syncthreads();
        if (tid < 128) {
            float gi = gpart[0][tid]       + gpart[1][tid];
            float gf = gpart[0][128 + tid] + gpart[1][128 + tid];
            float gg = gpart[0][256 + tid] + gpart[1][256 + tid];
            float go = gpart[0][384 + tid] + gpart[1][384 + tid];
            c = fsig(gf)*c + fsig(gi)*tanhf(gg);
            float h = fsig(go)*tanhf(c);
            h_lds[tid] = h;
            if (wAll) {
                int tout = flip ? (63 - t) : t;
                outp[((size_t)b*64 + tout)*128 + tid] = h;
            }
        }
        __syncthreads();
        xwc = xwn;
    }
    if (!wAll && tid < 128)
        outp[(size_t)b * a.outStride + tid] = h_lds[tid];
}

// ---------------- cosine matrix cm[b][i][j] between p_dir and q_dir rows ----------------
__global__ __launch_bounds__(256, 1)
void k_cos_matrix(const float* __restrict__ pfw, const float* __restrict__ pbw,
                  const float* __restrict__ qfw, const float* __restrict__ qbw,
                  float* __restrict__ cmf, float* __restrict__ cmb) {
    int b = blockIdx.x, dir = blockIdx.y;
    const float* h1 = (dir ? pbw : pfw) + (size_t)b*8192;
    const float* h2 = (dir ? qbw : qfw) + (size_t)b*8192;
    float* cm = (dir ? cmb : cmf) + (size_t)b*4096;
    __shared__ __align__(16) float A[64][132];
    __shared__ __align__(16) float Bt[64][132];
    __shared__ float n1[64], n2[64];
    int tid = threadIdx.x;
    for (int m = tid; m < 8192; m += 256) {
        int r = m >> 7, d = m & 127;
        A[r][d] = h1[m];
        Bt[r][d] = h2[m];
    }
    __syncthreads();
    if (tid < 128) {
        const float* row = (tid < 64) ? &A[tid][0] : &Bt[tid-64][0];
        float s = 0.f;
        #pragma unroll
        for (int k4 = 0; k4 < 32; ++k4) {
            float4 v = *(const float4*)&row[k4*4];
            s += v.x*v.x + v.y*v.y + v.z*v.z + v.w*v.w;
        }
        float nv = sqrtf(fmaxf(s, EPS));
        if (tid < 64) n1[tid] = nv; else n2[tid-64] = nv;
    }
    __syncthreads();
    int tx = tid & 15, ty = tid >> 4;
    float acc[4][4] = {};
    #pragma unroll
    for (int k4 = 0; k4 < 32; ++k4) {
        float4 av[4], bv[4];
        #pragma unroll
        for (int i = 0; i < 4; ++i) av[i] = *(const float4*)&A[ty + i*16][k4*4];
        #pragma unroll
        for (int j = 0; j < 4; ++j) bv[j] = *(const float4*)&Bt[tx + j*16][k4*4];
        #pragma unroll
        for (int i = 0; i < 4; ++i)
            #pragma unroll
            for (int j = 0; j < 4; ++j)
                acc[i][j] += av[i].x*bv[j].x + av[i].y*bv[j].y + av[i].z*bv[j].z + av[i].w*bv[j].w;
    }
    #pragma unroll
    for (int i = 0; i < 4; ++i) {
        int r = ty + i*16;
        #pragma unroll
        for (int j = 0; j < 4; ++j) {
            int c2 = tx + j*16;
            cm[r*64 + c2] = acc[i][j] / (n1[r]*n2[c2]);
        }
    }
}

// ---------------- full / attentive / max-attentive parts (6 of 8) ----------------
__global__ __launch_bounds__(512, 2)
void k_full_att(const float* __restrict__ pfw, const float* __restrict__ pbw,
                const float* __restrict__ qfw, const float* __restrict__ qbw,
                const float* __restrict__ cmf, const float* __restrict__ cmb,
                const float* __restrict__ mpmw,
                float* __restrict__ mp, float* __restrict__ mq) {
    int b = blockIdx.x, dir = blockIdx.y, which = blockIdx.z;
    const float* pd = (dir ? pbw : pfw) + (size_t)b*8192;
    const float* qd = (dir ? qbw : qfw) + (size_t)b*8192;
    const float* h1g = which ? qd : pd;
    const float* h2g = which ? pd : qd;
    const float* cmsrc = (dir ? cmb : cmf) + (size_t)b*4096;
    float* outb = which ? mq : mp;
    __shared__ __align__(16) float h2s[64][132];
    __shared__ float cms[64][68];
    __shared__ __align__(16) float wl[3*20*128];
    int tid = threadIdx.x;
    for (int m = tid; m < 8192; m += 512) {
        int r = m >> 7, d = m & 127;
        h2s[r][d] = h2g[m];
    }
    for (int m = tid; m < 4096; m += 512) {
        int l = m >> 6, j = m & 63;
        cms[l][j] = which ? cmsrc[j*64 + l] : cmsrc[m];
    }
    for (int m = tid; m < 2560; m += 512) {
        wl[m]        = mpmw[(size_t)(0+dir)*2560 + m];
        wl[2560 + m] = mpmw[(size_t)(2+dir)*2560 + m];
        wl[5120 + m] = mpmw[(size_t)(4+dir)*2560 + m];
    }
    __syncthreads();
    int l = tid >> 3, r = tid & 7;
    int d0 = r * 16;
    float h1d[16];
    #pragma unroll
    for (int q4 = 0; q4 < 4; ++q4) {
        float4 v = *(const float4*)&h1g[l*128 + d0 + q4*4];
        h1d[q4*4+0]=v.x; h1d[q4*4+1]=v.y; h1d[q4*4+2]=v.z; h1d[q4*4+3]=v.w;
    }
    float rsum = 0.f, bv = -3.4e38f; int bj = 64;
    for (int jj = 0; jj < 8; ++jj) {
        int j = r*8 + jj;
        float cv = cms[l][j];
        rsum += cv;
        if (cv > bv) { bv = cv; bj = j; }
    }
    #pragma unroll
    for (int m = 1; m < 8; m <<= 1) rsum += __shfl_xor(rsum, m, 8);
    #pragma unroll
    for (int m = 1; m < 8; m <<= 1) {
        float ov = __shfl_xor(bv, m, 8);
        int oj = __shfl_xor(bj, m, 8);
        if (ov > bv || (ov == bv && oj < bj)) { bv = ov; bj = oj; }
    }
    float att[16];
    #pragma unroll
    for (int dd = 0; dd < 16; ++dd) att[dd] = 0.f;
    for (int j = 0; j < 64; ++j) {
        float cv = cms[l][j];
        #pragma unroll
        for (int q4 = 0; q4 < 4; ++q4) {
            float4 hv = *(const float4*)&h2s[j][d0 + q4*4];
            att[q4*4+0] += cv*hv.x; att[q4*4+1] += cv*hv.y;
            att[q4*4+2] += cv*hv.z; att[q4*4+3] += cv*hv.w;
        }
    }
    float rinv = 1.f / (rsum + EPS);
    #pragma unroll
    for (int dd = 0; dd < 16; ++dd) att[dd] *= rinv;
    float mvd[16], h2l[16];
    #pragma unroll
    for (int q4 = 0; q4 < 4; ++q4) {
        float4 v = *(const float4*)&h2s[bj][d0 + q4*4];
        mvd[q4*4+0]=v.x; mvd[q4*4+1]=v.y; mvd[q4*4+2]=v.z; mvd[q4*4+3]=v.w;
        float4 u = *(const float4*)&h2s[63][d0 + q4*4];
        h2l[q4*4+0]=u.x; h2l[q4*4+1]=u.y; h2l[q4*4+2]=u.z; h2l[q4*4+3]=u.w;
    }
    size_t outrow = ((size_t)b*64 + l)*160;
    for (int pp = 0; pp < 20; ++pp) {
        const float* wf = &wl[pp*128 + d0];
        const float* wa = &wl[2560 + pp*128 + d0];
        const float* wm = &wl[5120 + pp*128 + d0];
        float fn=0,f1=0,f2=0, an=0,a1=0,a2=0, mn=0,m1=0,m2=0;
        #pragma unroll
        for (int dd = 0; dd < 16; ++dd) {
            float wfv = wf[dd], wav = wa[dd], wmv = wm[dd];
            float x1 = h1d[dd]*wfv, x2 = h2l[dd]*wfv;
            fn += x1*x2; f1 += x1*x1; f2 += x2*x2;
            float y1 = h1d[dd]*wav, y2 = att[dd]*wav;
            an += y1*y2; a1 += y1*y1; a2 += y2*y2;
            float z1 = h1d[dd]*wmv, z2 = mvd[dd]*wmv;
            mn += z1*z2; m1 += z1*z1; m2 += z2*z2;
        }
        #pragma unroll
        for (int m = 1; m < 8; m <<= 1) {
            fn += __shfl_xor(fn,m,8); f1 += __shfl_xor(f1,m,8); f2 += __shfl_xor(f2,m,8);
            an += __shfl_xor(an,m,8); a1 += __shfl_xor(a1,m,8); a2 += __shfl_xor(a2,m,8);
            mn += __shfl_xor(mn,m,8); m1 += __shfl_xor(m1,m,8); m2 += __shfl_xor(m2,m,8);
        }
        if (r == 0) {
            outb[outrow + (0+dir)*20 + pp] = fn / sqrtf(fmaxf(f1,EPS)) / sqrtf(fmaxf(f2,EPS));
            outb[outrow + (2+dir)*20 + pp] = an / sqrtf(fmaxf(a1,EPS)) / sqrtf(fmaxf(a2,EPS));
            outb[outrow + (4+dir)*20 + pp] = mn / sqrtf(fmaxf(m1,EPS)) / sqrtf(fmaxf(m2,EPS));
        }
    }
}

// ---------------- max-pool via split-f16 MFMA ----
__global__ __launch_bounds__(256, 1)
void k_maxpool_mfma(const float* __restrict__ pfw, const float* __restrict__ pbw,
                    const float* __restrict__ qfw, const float* __restrict__ qbw,
                    const float* __restrict__ mpmw,
                    float* __restrict__ mp, float* __restrict__ mq) {
    int b = blockIdx.x, dir = blockIdx.y, pph = blockIdx.z;
    const float* h1 = (dir ? pbw : pfw) + (size_t)b*8192;
    const float* h2 = (dir ? qbw : qfw) + (size_t)b*8192;
    __shared__ __align__(16) float h1s[64][132];
    __shared__ __align__(16) float h2s[64][132];
    __shared__ __align__(16) float w2s[32][132];
    __shared__ float n1s[64][25], n2s[64][25];
    __shared__ float cpart[4][68];
    int tid = threadIdx.x;
    int w = tid >> 6, l = tid & 63, lr = l & 15, lc = l >> 4;
    for (int m = tid; m < 8192; m += 256) {
        int r = m >> 7, d = m & 127;
        h1s[r][d] = h1[m];
        h2s[r][d] = h2[m];
    }
    for (int m = tid; m < 32*128; m += 256) {
        int r = m >> 7, d = m & 127;
        float v = (r < 20) ? mpmw[(size_t)((6+dir)*20 + r)*128 + d] : 0.f;
        w2s[r][d] = v * v;
    }
    __syncthreads();
    float a1[32], b1[32];
    #pragma unroll
    for (int kt = 0; kt < 4; ++kt) {
        *(float4*)&a1[kt*8]     = *(const float4*)&h1s[w*16 + lr][kt*32 + lc*8];
        *(float4*)&a1[kt*8 + 4] = *(const float4*)&h1s[w*16 + lr][kt*32 + lc*8 + 4];
        *(float4*)&b1[kt*8]     = *(const float4*)&h2s[w*16 + lr][kt*32 + lc*8];
        *(float4*)&b1[kt*8 + 4] = *(const float4*)&h2s[w*16 + lr][kt*32 + lc*8 + 4];
    }
    half8 Bh[4][4], Bl[4][4];
    #pragma unroll
    for (int nt = 0; nt < 4; ++nt)
        #pragma unroll
        for (int kt = 0; kt < 4; ++kt) {
            float tmp[8];
            *(float4*)&tmp[0] = *(const float4*)&h2s[nt*16 + lr][kt*32 + lc*8];
            *(float4*)&tmp[4] = *(const float4*)&h2s[nt*16 + lr][kt*32 + lc*8 + 4];
            split8_f16(tmp, Bh[nt][kt], Bl[nt][kt]);
        }
    {
        float sq[32];
        half8 s1h[4], s1l[4], s2h[4], s2l[4];
        #pragma unroll
        for (int kt = 0; kt < 4; ++kt) {
            #pragma unroll
            for (int e = 0; e < 8; ++e) sq[kt*8+e] = a1[kt*8+e]*a1[kt*8+e];
            split8_f16(&sq[kt*8], s1h[kt], s1l[kt]);
        }
        #pragma unroll
        for (int kt = 0; kt < 4; ++kt) {
            #pragma unroll
            for (int e = 0; e < 8; ++e) sq[kt*8+e] = b1[kt*8+e]*b1[kt*8+e];
            split8_f16(&sq[kt*8], s2h[kt], s2l[kt]);
        }
        half8 w2h[2][4], w2l[2][4];
        #pragma unroll
        for (int nt2 = 0; nt2 < 2; ++nt2)
            #pragma unroll
            for (int kt = 0; kt < 4; ++kt) {
                float tmp[8];
                *(float4*)&tmp[0] = *(const float4*)&w2s[nt2*16 + lr][kt*32 + lc*8];
                *(float4*)&tmp[4] = *(const float4*)&w2s[nt2*16 + lr][kt*32 + lc*8 + 4];
                split8_f16(tmp, w2h[nt2][kt], w2l[nt2][kt]);
            }
        #pragma unroll
        for (int nt2 = 0; nt2 < 2; ++nt2) {
            floatx4 na1 = {0.f,0.f,0.f,0.f}, na2 = {0.f,0.f,0.f,0.f};
            #pragma unroll
            for (int kt = 0; kt < 4; ++kt) {
                na1 = __builtin_amdgcn_mfma_f32_16x16x32_f16(s1h[kt], w2h[nt2][kt], na1, 0, 0, 0);
                na2 = __builtin_amdgcn_mfma_f32_16x16x32_f16(s2h[kt], w2h[nt2][kt], na2, 0, 0, 0);
            }
            #pragma unroll
            for (int kt = 0; kt < 4; ++kt) {
                na1 = __builtin_amdgcn_mfma_f32_16x16x32_f16(s1l[kt], w2h[nt2][kt], na1, 0, 0, 0);
                na2 = __builtin_amdgcn_mfma_f32_16x16x32_f16(s2l[kt], w2h[nt2][kt], na2, 0, 0, 0);
            }
            #pragma unroll
            for (int kt = 0; kt < 4; ++kt) {
                na1 = __builtin_amdgcn_mfma_f32_16x16x32_f16(s1h[kt], w2l[nt2][kt], na1, 0, 0, 0);
                na2 = __builtin_amdgcn_mfma_f32_16x16x32_f16(s2h[kt], w2l[nt2][kt], na2, 0, 0, 0);
            }
            #pragma unroll
            for (int i = 0; i < 4; ++i) {
                int row = w*16 + lc*4 + i;
                int c2 = nt2*16 + lr;
                if (c2 < 20) {
                    n1s[row][c2] = sqrtf(fmaxf(na1[i], EPS));
                    n2s[row][c2] = sqrtf(fmaxf(na2[i], EPS));
                }
            }
        }
    }
    __syncthreads();
    for (int pi = 0; pi < 10; ++pi) {
        int pp = pph*10 + pi;
        int col = (6+dir)*20 + pp;
        half8 ah[4], al[4];
        #pragma unroll
        for (int kt = 0; kt < 4; ++kt) {
            float wv[8], aw[8];
            *(float4*)&wv[0] = *(const float4*)&w2s[pp][kt*32 + lc*8];
            *(float4*)&wv[4] = *(const float4*)&w2s[pp][kt*32 + lc*8 + 4];
            #pragma unroll
            for (int e = 0; e < 8; ++e) aw[e] = a1[kt*8+e]*wv[e];
            split8_f16(aw, ah[kt], al[kt]);
        }
        float n1v[4];
        #pragma unroll
        for (int i = 0; i < 4; ++i) n1v[i] = n1s[w*16 + lc*4 + i][pp];
        float rmax[4] = {-3.4e38f, -3.4e38f, -3.4e38f, -3.4e38f};
        float cmx[4];
        #pragma unroll
        for (int nt = 0; nt < 4; ++nt) {
            floatx4 acc = {0.f,0.f,0.f,0.f};
            #pragma unroll
            for (int kt = 0; kt < 4; ++kt)
                acc = __builtin_amdgcn_mfma_f32_16x16x32_f16(ah[kt], Bh[nt][kt], acc, 0, 0, 0);
            #pragma unroll
            for (int kt = 0; kt < 4; ++kt)
                acc = __builtin_amdgcn_mfma_f32_16x16x32_f16(al[kt], Bh[nt][kt], acc, 0, 0, 0);
            #pragma unroll
            for (int kt = 0; kt < 4; ++kt)
                acc = __builtin_amdgcn_mfma_f32_16x16x32_f16(ah[kt], Bl[nt][kt], acc, 0, 0, 0);
            float n2v = n2s[nt*16 + lr][pp];
            float cm_ = -3.4e38f;
            #pragma unroll
            for (int i = 0; i < 4; ++i) {
                float cv = acc[i] / (n1v[i] * n2v);
                rmax[i] = fmaxf(rmax[i], cv);
                cm_ = fmaxf(cm_, cv);
            }
            cmx[nt] = cm_;
        }
        #pragma unroll
        for (int msk = 1; msk < 16; msk <<= 1)
            #pragma unroll
            for (int i = 0; i < 4; ++i) rmax[i] = fmaxf(rmax[i], __shfl_xor(rmax[i], msk));
        if (lr == 0) {
            #pragma unroll
            for (int i = 0; i < 4; ++i)
                mp[((size_t)b*64 + w*16 + lc*4 + i)*160 + col] = rmax[i];
        }
        #pragma unroll
        for (int msk = 16; msk < 64; msk <<= 1)
            #pragma unroll
            for (int nt = 0; nt < 4; ++nt) cmx[nt] = fmaxf(cmx[nt], __shfl_xor(cmx[nt], msk));
        if (lc == 0) {
            #pragma unroll
            for (int nt = 0; nt < 4; ++nt) cpart[w][nt*16 + lr] = cmx[nt];
        }
        __syncthreads();
        if (tid < 64) {
            float mv = fmaxf(fmaxf(cpart[0][tid], cpart[1][tid]),
                             fmaxf(cpart[2][tid], cpart[3][tid]));
            mq[((size_t)b*64 + tid)*160 + col] = mv;
        }
        __syncthreads();
    }
}

// ---------------- final FC ----------------
__global__ void k_fc(const float* __restrict__ xcat,
                     const float* __restrict__ fc1W, const float* __restrict__ fc1b,
                     const float* __restrict__ fc2W, const float* __restrict__ fc2b,
                     float* __restrict__ out) {
    int b = blockIdx.x;
    int tid = threadIdx.x;   // 256
    __shared__ float y[256];
    const float* x = xcat + (size_t)b*512;
    float acc = fc1b[tid];
    #pragma unroll 8
    for (int k4 = 0; k4 < 128; ++k4) {
        float4 wv = *(const float4*)&fc1W[(size_t)tid*512 + k4*4];
        float4 xv = *(const float4*)&x[k4*4];
        acc += wv.x*xv.x + wv.y*xv.y + wv.z*xv.z + wv.w*xv.w;
    }
    y[tid] = tanhf(acc);
    __syncthreads();
    if (tid < 2) {
        float o = fc2b[tid];
        for (int k = 0; k < 256; ++k) o += y[k]*fc2W[tid*256 + k];
        out[b*2 + tid] = o;
    }
}

extern "C" void kernel_launch(void* const* d_in, const int* in_sizes, int n_in,
                              void* d_out, int out_size, void* d_ws, size_t ws_size,
                              hipStream_t stream) {
    (void)in_sizes; (void)n_in; (void)out_size; (void)ws_size;
    const int* idxA  = (const int*)d_in[0];
    const int* idxB  = (const int*)d_in[1];
    const int* cidxA = (const int*)d_in[2];
    const int* cidxB = (const int*)d_in[3];
    const float* wemb = (const float*)d_in[4];
    const float* cemb = (const float*)d_in[5];
    const float* cWih = (const float*)d_in[6];
    const float* cWhh = (const float*)d_in[7];
    const float* cb   = (const float*)d_in[8];
    const float* xWf = (const float*)d_in[9];
    const float* xUf = (const float*)d_in[10];
    const float* xbf = (const float*)d_in[11];
    const float* xWb = (const float*)d_in[12];
    const float* xUb = (const float*)d_in[13];
    const float* xbb = (const float*)d_in[14];
    const float* aWf = (const float*)d_in[15];
    const float* aUf = (const float*)d_in[16];
    const float* abf = (const float*)d_in[17];
    const float* aWb = (const float*)d_in[18];
    const float* aUb = (const float*)d_in[19];
    const float* abb = (const float*)d_in[20];
    const float* mpmw = (const float*)d_in[21];
    const float* fc1W = (const float*)d_in[22];
    const float* fc1b = (const float*)d_in[23];
    const float* fc2W = (const float*)d_in[24];
    const float* fc2b = (const float*)d_in[25];
    float* out = (float*)d_out;

    float* ws = (float*)d_ws;
    float* xw0 = ws; ws += (size_t)4096*512;
    float* xw1 = ws; ws += (size_t)4096*512;
    float* xw2 = ws; ws += (size_t)4096*512;
    float* xw3 = ws; ws += (size_t)4096*512;
    float* pfw = ws; ws += (size_t)4096*128;
    float* pbw = ws; ws += (size_t)4096*128;
    float* qfw = ws; ws += (size_t)4096*128;
    float* qbw = ws; ws += (size_t)4096*128;
    float* cmf = ws; ws += (size_t)64*64*64;
    float* cmb = ws; ws += (size_t)64*64*64;
    float* mp  = ws; ws += (size_t)4096*160;
    float* mq  = ws; ws += (size_t)4096*160;
    float* xcat = ws; ws += (size_t)64*512;
    unsigned short* Xaug = (unsigned short*)ws; ws += (size_t)8192*1152/2;   // bf16 [8192][1152]
    unsigned short* Wfa  = (unsigned short*)ws; ws += (size_t)512*1152/2;
    unsigned short* Wba  = (unsigned short*)ws; ws += (size_t)512*1152/2;
    unsigned short* WihC = (unsigned short*)ws; ws += (size_t)256*192/2;
    unsigned short* WhhC = (unsigned short*)ws; ws += (size_t)256*192/2;

    // 0. char LSTM weight conversions
    k_conv<<<256, 128, 0, stream>>>(cWih, WihC, 64, 64, 1);
    k_conv<<<256, 128, 0, stream>>>(cWhh, WhhC, 64, 64, 1);
    // 1. word embedding gather -> Xaug (split-bf16), zero-pads cols 300..383
    k_embed_word<<<8192, 128, 0, stream>>>(idxA, idxB, wemb, Xaug);
    // 2. char LSTM via MFMA -> Xaug cols 300..363 (split-bf16)
    k_char_mfma<<<256, 256, 0, stream>>>(cidxA, cidxB, cemb, WihC, WhhC, cb, Xaug);
    // 3. ctx weight conversions
    k_conv<<<512, 128, 0, stream>>>(xWf, Wfa, 364, 384, 1);
    k_conv<<<512, 128, 0, stream>>>(xWb, Wba, 364, 384, 1);
    // 4. ctx input projections via MFMA (4 scans: A-f, B-f, A-b, B-b)
    MfArgs cx;
    cx.X = Xaug;
    cx.W[0]=Wfa; cx.W[1]=Wfa; cx.W[2]=Wba; cx.W[3]=Wba;
    cx.bias[0]=xbf; cx.bias[1]=xbf; cx.bias[2]=xbb; cx.bias[3]=xbb;
    cx.out[0]=xw0; cx.out[1]=xw1; cx.out[2]=xw2; cx.out[3]=xw3;
    cx.flip[0]=0; cx.flip[1]=0; cx.flip[2]=1; cx.flip[3]=1;
    cx.rowBase[0]=0; cx.rowBase[1]=4096; cx.rowBase[2]=0; cx.rowBase[3]=4096;
    cx.Kaug = 1152;
    k_xw_mfma<<<dim3(32, 4, 4), 256, 0, stream>>>(cx);
    // 5. ctx recurrences (1024-thread split-K scan, pk_fma, i/f-weights in LDS)
    ScanArgs cs;
    cs.xw[0]=xw0; cs.xw[1]=xw1; cs.xw[2]=xw2; cs.xw[3]=xw3;
    cs.whh[0]=xUf; cs.whh[1]=xUf; cs.whh[2]=xUb; cs.whh[3]=xUb;
    cs.out[0]=pfw; cs.out[1]=qfw; cs.out[2]=pbw; cs.out[3]=qbw;
    cs.flipOut[0]=0; cs.flipOut[1]=0; cs.flipOut[2]=1; cs.flipOut[3]=1;
    cs.writeAll = 1; cs.outStride = 0;
    k_lstm_scan<<<dim3(64, 4), 1024, 0, stream>>>(cs);
    // 6. cosine matrices (p vs q), fw and bw
    k_cos_matrix<<<dim3(64, 2), 256, 0, stream>>>(pfw, pbw, qfw, qbw, cmf, cmb);
    // 7. full / attentive / max-attentive parts for mp and mq
    k_full_att<<<dim3(64, 2, 2), 512, 0, stream>>>(pfw, pbw, qfw, qbw, cmf, cmb, mpmw, mp, mq);
    // 8. max-pool parts via MFMA (row-max -> mp, col-max -> mq)
    k_maxpool_mfma<<<dim3(64, 2, 2), 256, 0, stream>>>(pfw, pbw, qfw, qbw, mpmw, mp, mq);
    // 9. convert agg inputs/weights (reuse Xaug/Wfa/Wba buffers; Kaug=480)
    k_conv<<<4096, 128, 0, stream>>>(mp, Xaug, 160, 160, 0);
    k_conv<<<4096, 128, 0, stream>>>(mq, Xaug + (size_t)4096*480, 160, 160, 0);
    k_conv<<<512, 128, 0, stream>>>(aWf, Wfa, 160, 160, 1);
    k_conv<<<512, 128, 0, stream>>>(aWb, Wba, 160, 160, 1);
    // 10. agg input projections via MFMA
    MfArgs ax;
    ax.X = Xaug;
    ax.W[0]=Wfa; ax.W[1]=Wfa; ax.W[2]=Wba; ax.W[3]=Wba;
    ax.bias[0]=abf; ax.bias[1]=abf; ax.bias[2]=abb; ax.bias[3]=abb;
    ax.out[0]=xw0; ax.out[1]=xw1; ax.out[2]=xw2; ax.out[3]=xw3;
    ax.flip[0]=0; ax.flip[1]=0; ax.flip[2]=1; ax.flip[3]=1;
    ax.rowBase[0]=0; ax.rowBase[1]=4096; ax.rowBase[2]=0; ax.rowBase[3]=4096;
    ax.Kaug = 480;
    k_xw_mfma<<<dim3(32, 4, 4), 256, 0, stream>>>(ax);
    // 11. agg recurrences, final hidden only -> xcat [64][512]
    ScanArgs as;
    as.xw[0]=xw0; as.xw[1]=xw1; as.xw[2]=xw2; as.xw[3]=xw3;
    as.whh[0]=aUf; as.whh[1]=aUf; as.whh[2]=aUb; as.whh[3]=aUb;
    as.out[0]=xcat+0; as.out[1]=xcat+256; as.out[2]=xcat+128; as.out[3]=xcat+384;
    as.flipOut[0]=0; as.flipOut[1]=0; as.flipOut[2]=0; as.flipOut[3]=0;
    as.writeAll = 0; as.outStride = 512;
    k_lstm_scan<<<dim3(64, 4), 1024, 0, stream>>>(as);
    // 12. FC head
    k_fc<<<64, 256, 0, stream>>>(xcat, fc1W, fc1b, fc2W, fc2b, out);
}

// Round 13
// 368.983 us; speedup vs baseline: 3.6518x; 3.6518x over previous
//
#include <hip/hip_runtime.h>

#define EPS 1e-6f

typedef __attribute__((ext_vector_type(8))) short short8;
typedef __attribute__((ext_vector_type(8))) _Float16 half8;
typedef __attribute__((ext_vector_type(4))) float floatx4;
typedef __attribute__((ext_vector_type(2))) float floatx2;

struct ScanArgs {
    const float* xw[4];
    const float* whh[4];
    float* out[4];
    int flipOut[4];
    int writeAll;
    int outStride;
};

struct MfArgs {
    const unsigned short* X;        // [8192][Kaug] augmented bf16
    const unsigned short* W[4];     // [512][Kaug] augmented bf16
    const float* bias[4];
    float* out[4];                  // [4096][512] fp32
    int flip[4];
    int rowBase[4];
    int Kaug;
};

__device__ __forceinline__ float fsig(float x) { return 1.0f / (1.0f + __expf(-x)); }
__device__ __forceinline__ float tanh_fast(float x) {
    float e = __expf(2.f * x);
    return 1.f - 2.f / (e + 1.f);
}
__device__ __forceinline__ unsigned short f2bf(float x) {
    unsigned u = __float_as_uint(x);
    return (unsigned short)((u + 0x7fffu + ((u >> 16) & 1u)) >> 16);
}
__device__ __forceinline__ void split8_bf(const float* p, short8& hi, short8& lo) {
    #pragma unroll
    for (int e = 0; e < 8; ++e) {
        unsigned short h = f2bf(p[e]);
        float hf = __uint_as_float((unsigned)h << 16);
        hi[e] = (short)h;
        lo[e] = (short)f2bf(p[e] - hf);
    }
}
__device__ __forceinline__ void split8_f16(const float* p, half8& hi, half8& lo) {
    #pragma unroll
    for (int e = 0; e < 8; ++e) {
        _Float16 h = (_Float16)p[e];
        hi[e] = h;
        lo[e] = (_Float16)(p[e] - (float)h);
    }
}
__device__ __forceinline__ floatx2 pk_fma(floatx2 a, floatx2 b, floatx2 c) {
    floatx2 d;
    asm("v_pk_fma_f32 %0, %1, %2, %3" : "=v"(d) : "v"(a), "v"(b), "v"(c));
    return d;
}

// ---------------- word embedding gather -> split-bf16 Xaug directly ----------------
__global__ void k_embed_word(const int* __restrict__ idxA, const int* __restrict__ idxB,
                             const float* __restrict__ emb,
                             unsigned short* __restrict__ Xaug) {
    int row = blockIdx.x;              // 0..8191 (A rows 0..4095, B rows 4096..8191)
    const int* idx = (row < 4096) ? idxA : idxB;
    int r = row & 4095;
    size_t e = (size_t)idx[r];
    const float* src = emb + e * 300;
    unsigned short* d = Xaug + (size_t)row * 1152;
    for (int k = threadIdx.x; k < 384; k += blockDim.x) {
        float x = (k < 300) ? src[k] : 0.f;
        unsigned short hr = f2bf(x);
        float hif = __uint_as_float((unsigned)hr << 16);
        unsigned short lr2 = f2bf(x - hif);
        d[k]       = hr;
        d[384 + k] = lr2;
        d[768 + k] = hr;
    }
}

// ---------------- fp32 -> augmented split-bf16 (X: [hi|lo|hi], W: [hi|hi|lo]) ------------
__global__ void k_conv(const float* __restrict__ src, unsigned short* __restrict__ dst,
                       int K, int Ksec, int isW) {
    int row = blockIdx.x;
    const float* s = src + (size_t)row * K;
    unsigned short* d = dst + (size_t)row * (3 * Ksec);
    int o1 = (isW ? 2 : 1) * Ksec;   // where lo goes
    int o2 = (isW ? 1 : 2) * Ksec;   // where second hi goes
    for (int k = threadIdx.x; k < Ksec; k += blockDim.x) {
        float x = (k < K) ? s[k] : 0.f;
        unsigned short hr = f2bf(x);
        float hif = __uint_as_float((unsigned)hr << 16);
        unsigned short lr2 = f2bf(x - hif);
        d[k]      = hr;
        d[o1 + k] = lr2;
        d[o2 + k] = hr;
    }
}

// ---------------- char LSTM via MFMA: 32 seqs/block -> split-bf16 Xaug cols 300..363 -----
__global__ __launch_bounds__(256, 1)
void k_char_mfma(const int* __restrict__ cidxA, const int* __restrict__ cidxB,
                 const float* __restrict__ emb,
                 const unsigned short* __restrict__ WihA, const unsigned short* __restrict__ WhhA,
                 const float* __restrict__ bias,
                 unsigned short* __restrict__ Xaug) {
    __shared__ __align__(16) float xs[32][68];
    __shared__ __align__(16) float hs[32][68];
    int tid = threadIdx.x;
    int w = tid >> 6, l = tid & 63, lr = l & 15, lc = l >> 4;
    int j = w * 16 + lr;              // h-dim column this lane covers
    short8 wih[4][6], whh[4][6];
    #pragma unroll
    for (int g = 0; g < 4; ++g)
        #pragma unroll
        for (int kt = 0; kt < 6; ++kt) {
            wih[g][kt] = *(const short8*)&WihA[(size_t)(g*64 + j)*192 + kt*32 + lc*8];
            whh[g][kt] = *(const short8*)&WhhA[(size_t)(g*64 + j)*192 + kt*32 + lc*8];
        }
    float bg[4];
    #pragma unroll
    for (int g = 0; g < 4; ++g) bg[g] = bias[g*64 + j];
    int seq0 = blockIdx.x * 32;
    for (int m = tid; m < 32*68; m += 256) (&hs[0][0])[m] = 0.f;
    float cst[2][4] = {};
    float hlast[2][4];
    __syncthreads();
    for (int t = 0; t < 8; ++t) {
        {
            int s = tid >> 3, ch = tid & 7;
            int sq = seq0 + s;
            const int* ci = (sq < 4096) ? cidxA : cidxB;
            int e = ci[(sq & 4095)*8 + t];
            float4 v0 = *(const float4*)&emb[(size_t)e*64 + ch*8];
            float4 v1 = *(const float4*)&emb[(size_t)e*64 + ch*8 + 4];
            *(float4*)&xs[s][ch*8] = v0;
            *(float4*)&xs[s][ch*8 + 4] = v1;
        }
        short8 hhi[2][2], hlo[2][2];
        if (t > 0) {
            #pragma unroll
            for (int mt = 0; mt < 2; ++mt)
                #pragma unroll
                for (int kt = 0; kt < 2; ++kt) {
                    float tmp[8];
                    *(float4*)&tmp[0] = *(const float4*)&hs[mt*16 + lr][kt*32 + lc*8];
                    *(float4*)&tmp[4] = *(const float4*)&hs[mt*16 + lr][kt*32 + lc*8 + 4];
                    split8_bf(tmp, hhi[mt][kt], hlo[mt][kt]);
                }
        }
        __syncthreads();   // A: xs staged; hs reads done
        short8 xhi[2][2], xlo[2][2];
        #pragma unroll
        for (int mt = 0; mt < 2; ++mt)
            #pragma unroll
            for (int kt = 0; kt < 2; ++kt) {
                float tmp[8];
                *(float4*)&tmp[0] = *(const float4*)&xs[mt*16 + lr][kt*32 + lc*8];
                *(float4*)&tmp[4] = *(const float4*)&xs[mt*16 + lr][kt*32 + lc*8 + 4];
                split8_bf(tmp, xhi[mt][kt], xlo[mt][kt]);
            }
        #pragma unroll
        for (int mt = 0; mt < 2; ++mt)
            #pragma unroll
            for (int g = 0; g < 4; ++g) {
                floatx4 a = {bg[g], bg[g], bg[g], bg[g]};
                a = __builtin_amdgcn_mfma_f32_16x16x32_bf16(xhi[mt][0], wih[g][0], a, 0, 0, 0);
                a = __builtin_amdgcn_mfma_f32_16x16x32_bf16(xhi[mt][1], wih[g][1], a, 0, 0, 0);
                a = __builtin_amdgcn_mfma_f32_16x16x32_bf16(xlo[mt][0], wih[g][2], a, 0, 0, 0);
                a = __builtin_amdgcn_mfma_f32_16x16x32_bf16(xlo[mt][1], wih[g][3], a, 0, 0, 0);
                a = __builtin_amdgcn_mfma_f32_16x16x32_bf16(xhi[mt][0], wih[g][4], a, 0, 0, 0);
                a = __builtin_amdgcn_mfma_f32_16x16x32_bf16(xhi[mt][1], wih[g][5], a, 0, 0, 0);
                if (t > 0) {
                    a = __builtin_amdgcn_mfma_f32_16x16x32_bf16(hhi[mt][0], whh[g][0], a, 0, 0, 0);
                    a = __builtin_amdgcn_mfma_f32_16x16x32_bf16(hhi[mt][1], whh[g][1], a, 0, 0, 0);
                    a = __builtin_amdgcn_mfma_f32_16x16x32_bf16(hlo[mt][0], whh[g][2], a, 0, 0, 0);
                    a = __builtin_amdgcn_mfma_f32_16x16x32_bf16(hlo[mt][1], whh[g][3], a, 0, 0, 0);
                    a = __builtin_amdgcn_mfma_f32_16x16x32_bf16(hhi[mt][0], whh[g][4], a, 0, 0, 0);
                    a = __builtin_amdgcn_mfma_f32_16x16x32_bf16(hhi[mt][1], whh[g][5], a, 0, 0, 0);
                }
                if (g == 0) { hlast[mt][0] = a[0]; hlast[mt][1] = a[1]; hlast[mt][2] = a[2]; hlast[mt][3] = a[3]; }
                else if (g == 1) {
                    #pragma unroll
                    for (int i = 0; i < 4; ++i) cst[mt][i] = fsig(a[i]) * cst[mt][i];
                } else if (g == 2) {
                    #pragma unroll
                    for (int i = 0; i < 4; ++i) cst[mt][i] += fsig(hlast[mt][i]) * tanh_fast(a[i]);
                } else {
                    #pragma unroll
                    for (int i = 0; i < 4; ++i) {
                        float h = fsig(a[i]) * tanh_fast(cst[mt][i]);
                        hlast[mt][i] = h;
                        hs[mt*16 + lc*4 + i][j] = h;
                    }
                }
            }
        __syncthreads();   // B: hs writes visible; xs reads done
    }
    #pragma unroll
    for (int mt = 0; mt < 2; ++mt)
        #pragma unroll
        for (int i = 0; i < 4; ++i) {
            int s = mt*16 + lc*4 + i;
            int sq = seq0 + s;                     // global Xaug row
            unsigned short* d = Xaug + (size_t)sq * 1152;
            float h = hlast[mt][i];
            unsigned short hh = f2bf(h);
            float hf = __uint_as_float((unsigned)hh << 16);
            unsigned short hl = f2bf(h - hf);
            int k = 300 + j;
            d[k]       = hh;
            d[384 + k] = hl;
            d[768 + k] = hh;
        }
}

// ---------------- MFMA input-projection GEMM: out[row][n] = bias[n] + sum_k X[srow][k]*W[n][k]
__global__ __launch_bounds__(256, 2)
void k_xw_mfma(MfArgs a) {
    int scan = blockIdx.z;
    const unsigned short* X = a.X;
    const unsigned short* W = a.W[scan];
    const float* bias = a.bias[scan];
    float* out = a.out[scan];
    int flip = a.flip[scan];
    int rowBase = a.rowBase[scan];
    int Kaug = a.Kaug;
    int m0 = blockIdx.x * 128;
    int n0 = blockIdx.y * 128;
    __shared__ __align__(16) unsigned short As[128][40];
    __shared__ __align__(16) unsigned short Bs[128][40];
    int tid = threadIdx.x;
    int wv = tid >> 6, lane = tid & 63;
    int lr = lane & 15, lc = lane >> 4;

    floatx4 acc[2][8];
    #pragma unroll
    for (int f = 0; f < 2; ++f)
        #pragma unroll
        for (int g = 0; g < 8; ++g)
            acc[f][g] = (floatx4){0.f, 0.f, 0.f, 0.f};

    int r0 = m0 + (tid >> 2);
    int r1 = r0 + 64;
    int sr0 = rowBase + (flip ? ((r0 & ~63) | (63 - (r0 & 63))) : r0);
    int sr1 = rowBase + (flip ? ((r1 & ~63) | (63 - (r1 & 63))) : r1);
    size_t asrc0 = (size_t)sr0 * Kaug + (tid & 3) * 8;
    size_t asrc1 = (size_t)sr1 * Kaug + (tid & 3) * 8;
    size_t bsrc0 = (size_t)(n0 + (tid >> 2)) * Kaug + (tid & 3) * 8;
    size_t bsrc1 = (size_t)(n0 + (tid >> 2) + 64) * Kaug + (tid & 3) * 8;
    int swrow = tid >> 2, swcol = (tid & 3) * 8;

    for (int k0 = 0; k0 < Kaug; k0 += 32) {
        short8 a0 = *(const short8*)(X + asrc0 + k0);
        short8 a1 = *(const short8*)(X + asrc1 + k0);
        short8 b0 = *(const short8*)(W + bsrc0 + k0);
        short8 b1 = *(const short8*)(W + bsrc1 + k0);
        __syncthreads();
        *(short8*)&As[swrow][swcol]      = a0;
        *(short8*)&As[swrow + 64][swcol] = a1;
        *(short8*)&Bs[swrow][swcol]      = b0;
        *(short8*)&Bs[swrow + 64][swcol] = b1;
        __syncthreads();
        short8 af0 = *(const short8*)&As[wv*32 + lr][lc*8];
        short8 af1 = *(const short8*)&As[wv*32 + 16 + lr][lc*8];
        #pragma unroll
        for (int g = 0; g < 8; ++g) {
            short8 bf = *(const short8*)&Bs[g*16 + lr][lc*8];
            acc[0][g] = __builtin_amdgcn_mfma_f32_16x16x32_bf16(af0, bf, acc[0][g], 0, 0, 0);
            acc[1][g] = __builtin_amdgcn_mfma_f32_16x16x32_bf16(af1, bf, acc[1][g], 0, 0, 0);
        }
    }

    #pragma unroll
    for (int f = 0; f < 2; ++f) {
        int row = m0 + wv*32 + f*16 + lc*4;
        #pragma unroll
        for (int g = 0; g < 8; ++g) {
            int col = n0 + g*16 + lr;
            float bv = bias[col];
            #pragma unroll
            for (int i = 0; i < 4; ++i)
                out[(size_t)(row + i)*512 + col] = acc[f][g][i] + bv;
        }
    }
}

// ---------------- LSTM recurrence: 1024 threads, split-K, packed-fp32 FMA (r9 version) ----
__global__ __launch_bounds__(1024, 4)
void k_lstm_scan(ScanArgs a) {
    int b = blockIdx.x;
    int scan = blockIdx.y;
    int tid = threadIdx.x;
    int p = tid >> 9;                  // K-half 0/1
    int g = tid & 511;                 // gate row
    __shared__ __align__(16) float h_lds[128];
    __shared__ float gpart[2][512];
    const float* W = a.whh[scan] + (size_t)g*128 + p*64;
    floatx2 w2[32];
    #pragma unroll
    for (int k = 0; k < 32; ++k) w2[k] = *(const floatx2*)&W[k*2];
    const float* xw = a.xw[scan] + (size_t)b*64*512;
    float* outp = a.out[scan];
    int flip = a.flipOut[scan];
    int wAll = a.writeAll;
    float c = 0.f;
    if (tid < 128) h_lds[tid] = 0.f;
    __syncthreads();
    const float* hb = &h_lds[p*64];
    float xwc = (p == 0) ? xw[g] : 0.f;
    for (int t = 0; t < 64; ++t) {
        float xwn = 0.f;
        if (p == 0 && t < 63) xwn = xw[(size_t)(t+1)*512 + g];
        floatx2 a0 = {0.f,0.f}, a1 = {0.f,0.f}, a2 = {0.f,0.f}, a3 = {0.f,0.f};
        #pragma unroll
        for (int kk = 0; kk < 8; ++kk) {
            floatx4 u = *(const floatx4*)&hb[kk*8];
            floatx4 v = *(const floatx4*)&hb[kk*8 + 4];
            a0 = pk_fma(w2[kk*4+0], __builtin_shufflevector(u, u, 0, 1), a0);
            a1 = pk_fma(w2[kk*4+1], __builtin_shufflevector(u, u, 2, 3), a1);
            a2 = pk_fma(w2[kk*4+2], __builtin_shufflevector(v, v, 0, 1), a2);
            a3 = pk_fma(w2[kk*4+3], __builtin_shufflevector(v, v, 2, 3), a3);
        }
        float s = ((a0.x + a0.y) + (a1.x + a1.y)) + ((a2.x + a2.y) + (a3.x + a3.y));
        gpart[p][g] = xwc + s;
        __syncthreads();
        if (tid < 128) {
            float gi = gpart[0][tid]       + gpart[1][tid];
            float gf = gpart[0][128 + tid] + gpart[1][128 + tid];
            float gg = gpart[0][256 + tid] + gpart[1][256 + tid];
            float go = gpart[0][384 + tid] + gpart[1][384 + tid];
            c = fsig(gf)*c + fsig(gi)*tanhf(gg);
            float h = fsig(go)*tanhf(c);
            h_lds[tid] = h;
            if (wAll) {
                int tout = flip ? (63 - t) : t;
                outp[((size_t)b*64 + tout)*128 + tid] = h;
            }
        }
        __syncthreads();
        xwc = xwn;
    }
    if (!wAll && tid < 128)
        outp[(size_t)b * a.outStride + tid] = h_lds[tid];
}

// ---------------- cosine matrix cm[b][i][j] between p_dir and q_dir rows ----------------
__global__ __launch_bounds__(256, 1)
void k_cos_matrix(const float* __restrict__ pfw, const float* __restrict__ pbw,
                  const float* __restrict__ qfw, const float* __restrict__ qbw,
                  float* __restrict__ cmf, float* __restrict__ cmb) {
    int b = blockIdx.x, dir = blockIdx.y;
    const float* h1 = (dir ? pbw : pfw) + (size_t)b*8192;
    const float* h2 = (dir ? qbw : qfw) + (size_t)b*8192;
    float* cm = (dir ? cmb : cmf) + (size_t)b*4096;
    __shared__ __align__(16) float A[64][132];
    __shared__ __align__(16) float Bt[64][132];
    __shared__ float n1[64], n2[64];
    int tid = threadIdx.x;
    for (int m = tid; m < 8192; m += 256) {
        int r = m >> 7, d = m & 127;
        A[r][d] = h1[m];
        Bt[r][d] = h2[m];
    }
    __syncthreads();
    if (tid < 128) {
        const float* row = (tid < 64) ? &A[tid][0] : &Bt[tid-64][0];
        float s = 0.f;
        #pragma unroll
        for (int k4 = 0; k4 < 32; ++k4) {
            float4 v = *(const float4*)&row[k4*4];
            s += v.x*v.x + v.y*v.y + v.z*v.z + v.w*v.w;
        }
        float nv = sqrtf(fmaxf(s, EPS));
        if (tid < 64) n1[tid] = nv; else n2[tid-64] = nv;
    }
    __syncthreads();
    int tx = tid & 15, ty = tid >> 4;
    float acc[4][4] = {};
    #pragma unroll
    for (int k4 = 0; k4 < 32; ++k4) {
        float4 av[4], bv[4];
        #pragma unroll
        for (int i = 0; i < 4; ++i) av[i] = *(const float4*)&A[ty + i*16][k4*4];
        #pragma unroll
        for (int j = 0; j < 4; ++j) bv[j] = *(const float4*)&Bt[tx + j*16][k4*4];
        #pragma unroll
        for (int i = 0; i < 4; ++i)
            #pragma unroll
            for (int j = 0; j < 4; ++j)
                acc[i][j] += av[i].x*bv[j].x + av[i].y*bv[j].y + av[i].z*bv[j].z + av[i].w*bv[j].w;
    }
    #pragma unroll
    for (int i = 0; i < 4; ++i) {
        int r = ty + i*16;
        #pragma unroll
        for (int j = 0; j < 4; ++j) {
            int c2 = tx + j*16;
            cm[r*64 + c2] = acc[i][j] / (n1[r]*n2[c2]);
        }
    }
}

// ---------------- full / attentive / max-attentive parts (6 of 8) ----------------
__global__ __launch_bounds__(512, 2)
void k_full_att(const float* __restrict__ pfw, const float* __restrict__ pbw,
                const float* __restrict__ qfw, const float* __restrict__ qbw,
                const float* __restrict__ cmf, const float* __restrict__ cmb,
                const float* __restrict__ mpmw,
                float* __restrict__ mp, float* __restrict__ mq) {
    int b = blockIdx.x, dir = blockIdx.y, which = blockIdx.z;
    const float* pd = (dir ? pbw : pfw) + (size_t)b*8192;
    const float* qd = (dir ? qbw : qfw) + (size_t)b*8192;
    const float* h1g = which ? qd : pd;
    const float* h2g = which ? pd : qd;
    const float* cmsrc = (dir ? cmb : cmf) + (size_t)b*4096;
    float* outb = which ? mq : mp;
    __shared__ __align__(16) float h2s[64][132];
    __shared__ float cms[64][68];
    __shared__ __align__(16) float wl[3*20*128];
    int tid = threadIdx.x;
    for (int m = tid; m < 8192; m += 512) {
        int r = m >> 7, d = m & 127;
        h2s[r][d] = h2g[m];
    }
    for (int m = tid; m < 4096; m += 512) {
        int l = m >> 6, j = m & 63;
        cms[l][j] = which ? cmsrc[j*64 + l] : cmsrc[m];
    }
    for (int m = tid; m < 2560; m += 512) {
        wl[m]        = mpmw[(size_t)(0+dir)*2560 + m];
        wl[2560 + m] = mpmw[(size_t)(2+dir)*2560 + m];
        wl[5120 + m] = mpmw[(size_t)(4+dir)*2560 + m];
    }
    __syncthreads();
    int l = tid >> 3, r = tid & 7;
    int d0 = r * 16;
    float h1d[16];
    #pragma unroll
    for (int q4 = 0; q4 < 4; ++q4) {
        float4 v = *(const float4*)&h1g[l*128 + d0 + q4*4];
        h1d[q4*4+0]=v.x; h1d[q4*4+1]=v.y; h1d[q4*4+2]=v.z; h1d[q4*4+3]=v.w;
    }
    float rsum = 0.f, bv = -3.4e38f; int bj = 64;
    for (int jj = 0; jj < 8; ++jj) {
        int j = r*8 + jj;
        float cv = cms[l][j];
        rsum += cv;
        if (cv > bv) { bv = cv; bj = j; }
    }
    #pragma unroll
    for (int m = 1; m < 8; m <<= 1) rsum += __shfl_xor(rsum, m, 8);
    #pragma unroll
    for (int m = 1; m < 8; m <<= 1) {
        float ov = __shfl_xor(bv, m, 8);
        int oj = __shfl_xor(bj, m, 8);
        if (ov > bv || (ov == bv && oj < bj)) { bv = ov; bj = oj; }
    }
    float att[16];
    #pragma unroll
    for (int dd = 0; dd < 16; ++dd) att[dd] = 0.f;
    for (int j = 0; j < 64; ++j) {
        float cv = cms[l][j];
        #pragma unroll
        for (int q4 = 0; q4 < 4; ++q4) {
            float4 hv = *(const float4*)&h2s[j][d0 + q4*4];
            att[q4*4+0] += cv*hv.x; att[q4*4+1] += cv*hv.y;
            att[q4*4+2] += cv*hv.z; att[q4*4+3] += cv*hv.w;
        }
    }
    float rinv = 1.f / (rsum + EPS);
    #pragma unroll
    for (int dd = 0; dd < 16; ++dd) att[dd] *= rinv;
    float mvd[16], h2l[16];
    #pragma unroll
    for (int q4 = 0; q4 < 4; ++q4) {
        float4 v = *(const float4*)&h2s[bj][d0 + q4*4];
        mvd[q4*4+0]=v.x; mvd[q4*4+1]=v.y; mvd[q4*4+2]=v.z; mvd[q4*4+3]=v.w;
        float4 u = *(const float4*)&h2s[63][d0 + q4*4];
        h2l[q4*4+0]=u.x; h2l[q4*4+1]=u.y; h2l[q4*4+2]=u.z; h2l[q4*4+3]=u.w;
    }
    size_t outrow = ((size_t)b*64 + l)*160;
    for (int pp = 0; pp < 20; ++pp) {
        const float* wf = &wl[pp*128 + d0];
        const float* wa = &wl[2560 + pp*128 + d0];
        const float* wm = &wl[5120 + pp*128 + d0];
        float fn=0,f1=0,f2=0, an=0,a1=0,a2=0, mn=0,m1=0,m2=0;
        #pragma unroll
        for (int dd = 0; dd < 16; ++dd) {
            float wfv = wf[dd], wav = wa[dd], wmv = wm[dd];
            float x1 = h1d[dd]*wfv, x2 = h2l[dd]*wfv;
            fn += x1*x2; f1 += x1*x1; f2 += x2*x2;
            float y1 = h1d[dd]*wav, y2 = att[dd]*wav;
            an += y1*y2; a1 += y1*y1; a2 += y2*y2;
            float z1 = h1d[dd]*wmv, z2 = mvd[dd]*wmv;
            mn += z1*z2; m1 += z1*z1; m2 += z2*z2;
        }
        #pragma unroll
        for (int m = 1; m < 8; m <<= 1) {
            fn += __shfl_xor(fn,m,8); f1 += __shfl_xor(f1,m,8); f2 += __shfl_xor(f2,m,8);
            an += __shfl_xor(an,m,8); a1 += __shfl_xor(a1,m,8); a2 += __shfl_xor(a2,m,8);
            mn += __shfl_xor(mn,m,8); m1 += __shfl_xor(m1,m,8); m2 += __shfl_xor(m2,m,8);
        }
        if (r == 0) {
            outb[outrow + (0+dir)*20 + pp] = fn / sqrtf(fmaxf(f1,EPS)) / sqrtf(fmaxf(f2,EPS));
            outb[outrow + (2+dir)*20 + pp] = an / sqrtf(fmaxf(a1,EPS)) / sqrtf(fmaxf(a2,EPS));
            outb[outrow + (4+dir)*20 + pp] = mn / sqrtf(fmaxf(m1,EPS)) / sqrtf(fmaxf(m2,EPS));
        }
    }
}

// ---------------- max-pool via split-f16 MFMA ----
__global__ __launch_bounds__(256, 1)
void k_maxpool_mfma(const float* __restrict__ pfw, const float* __restrict__ pbw,
                    const float* __restrict__ qfw, const float* __restrict__ qbw,
                    const float* __restrict__ mpmw,
                    float* __restrict__ mp, float* __restrict__ mq) {
    int b = blockIdx.x, dir = blockIdx.y, pph = blockIdx.z;
    const float* h1 = (dir ? pbw : pfw) + (size_t)b*8192;
    const float* h2 = (dir ? qbw : qfw) + (size_t)b*8192;
    __shared__ __align__(16) float h1s[64][132];
    __shared__ __align__(16) float h2s[64][132];
    __shared__ __align__(16) float w2s[32][132];
    __shared__ float n1s[64][25], n2s[64][25];
    __shared__ float cpart[4][68];
    int tid = threadIdx.x;
    int w = tid >> 6, l = tid & 63, lr = l & 15, lc = l >> 4;
    for (int m = tid; m < 8192; m += 256) {
        int r = m >> 7, d = m & 127;
        h1s[r][d] = h1[m];
        h2s[r][d] = h2[m];
    }
    for (int m = tid; m < 32*128; m += 256) {
        int r = m >> 7, d = m & 127;
        float v = (r < 20) ? mpmw[(size_t)((6+dir)*20 + r)*128 + d] : 0.f;
        w2s[r][d] = v * v;
    }
    __syncthreads();
    float a1[32], b1[32];
    #pragma unroll
    for (int kt = 0; kt < 4; ++kt) {
        *(float4*)&a1[kt*8]     = *(const float4*)&h1s[w*16 + lr][kt*32 + lc*8];
        *(float4*)&a1[kt*8 + 4] = *(const float4*)&h1s[w*16 + lr][kt*32 + lc*8 + 4];
        *(float4*)&b1[kt*8]     = *(const float4*)&h2s[w*16 + lr][kt*32 + lc*8];
        *(float4*)&b1[kt*8 + 4] = *(const float4*)&h2s[w*16 + lr][kt*32 + lc*8 + 4];
    }
    half8 Bh[4][4], Bl[4][4];
    #pragma unroll
    for (int nt = 0; nt < 4; ++nt)
        #pragma unroll
        for (int kt = 0; kt < 4; ++kt) {
            float tmp[8];
            *(float4*)&tmp[0] = *(const float4*)&h2s[nt*16 + lr][kt*32 + lc*8];
            *(float4*)&tmp[4] = *(const float4*)&h2s[nt*16 + lr][kt*32 + lc*8 + 4];
            split8_f16(tmp, Bh[nt][kt], Bl[nt][kt]);
        }
    {
        float sq[32];
        half8 s1h[4], s1l[4], s2h[4], s2l[4];
        #pragma unroll
        for (int kt = 0; kt < 4; ++kt) {
            #pragma unroll
            for (int e = 0; e < 8; ++e) sq[kt*8+e] = a1[kt*8+e]*a1[kt*8+e];
            split8_f16(&sq[kt*8], s1h[kt], s1l[kt]);
        }
        #pragma unroll
        for (int kt = 0; kt < 4; ++kt) {
            #pragma unroll
            for (int e = 0; e < 8; ++e) sq[kt*8+e] = b1[kt*8+e]*b1[kt*8+e];
            split8_f16(&sq[kt*8], s2h[kt], s2l[kt]);
        }
        half8 w2h[2][4], w2l[2][4];
        #pragma unroll
        for (int nt2 = 0; nt2 < 2; ++nt2)
            #pragma unroll
            for (int kt = 0; kt < 4; ++kt) {
                float tmp[8];
                *(float4*)&tmp[0] = *(const float4*)&w2s[nt2*16 + lr][kt*32 + lc*8];
                *(float4*)&tmp[4] = *(const float4*)&w2s[nt2*16 + lr][kt*32 + lc*8 + 4];
                split8_f16(tmp, w2h[nt2][kt], w2l[nt2][kt]);
            }
        #pragma unroll
        for (int nt2 = 0; nt2 < 2; ++nt2) {
            floatx4 na1 = {0.f,0.f,0.f,0.f}, na2 = {0.f,0.f,0.f,0.f};
            #pragma unroll
            for (int kt = 0; kt < 4; ++kt) {
                na1 = __builtin_amdgcn_mfma_f32_16x16x32_f16(s1h[kt], w2h[nt2][kt], na1, 0, 0, 0);
                na2 = __builtin_amdgcn_mfma_f32_16x16x32_f16(s2h[kt], w2h[nt2][kt], na2, 0, 0, 0);
            }
            #pragma unroll
            for (int kt = 0; kt < 4; ++kt) {
                na1 = __builtin_amdgcn_mfma_f32_16x16x32_f16(s1l[kt], w2h[nt2][kt], na1, 0, 0, 0);
                na2 = __builtin_amdgcn_mfma_f32_16x16x32_f16(s2l[kt], w2h[nt2][kt], na2, 0, 0, 0);
            }
            #pragma unroll
            for (int kt = 0; kt < 4; ++kt) {
                na1 = __builtin_amdgcn_mfma_f32_16x16x32_f16(s1h[kt], w2l[nt2][kt], na1, 0, 0, 0);
                na2 = __builtin_amdgcn_mfma_f32_16x16x32_f16(s2h[kt], w2l[nt2][kt], na2, 0, 0, 0);
            }
            #pragma unroll
            for (int i = 0; i < 4; ++i) {
                int row = w*16 + lc*4 + i;
                int c2 = nt2*16 + lr;
                if (c2 < 20) {
                    n1s[row][c2] = sqrtf(fmaxf(na1[i], EPS));
                    n2s[row][c2] = sqrtf(fmaxf(na2[i], EPS));
                }
            }
        }
    }
    __syncthreads();
    for (int pi = 0; pi < 10; ++pi) {
        int pp = pph*10 + pi;
        int col = (6+dir)*20 + pp;
        half8 ah[4], al[4];
        #pragma unroll
        for (int kt = 0; kt < 4; ++kt) {
            float wv[8], aw[8];
            *(float4*)&wv[0] = *(const float4*)&w2s[pp][kt*32 + lc*8];
            *(float4*)&wv[4] = *(const float4*)&w2s[pp][kt*32 + lc*8 + 4];
            #pragma unroll
            for (int e = 0; e < 8; ++e) aw[e] = a1[kt*8+e]*wv[e];
            split8_f16(aw, ah[kt], al[kt]);
        }
        float n1v[4];
        #pragma unroll
        for (int i = 0; i < 4; ++i) n1v[i] = n1s[w*16 + lc*4 + i][pp];
        float rmax[4] = {-3.4e38f, -3.4e38f, -3.4e38f, -3.4e38f};
        float cmx[4];
        #pragma unroll
        for (int nt = 0; nt < 4; ++nt) {
            floatx4 acc = {0.f,0.f,0.f,0.f};
            #pragma unroll
            for (int kt = 0; kt < 4; ++kt)
                acc = __builtin_amdgcn_mfma_f32_16x16x32_f16(ah[kt], Bh[nt][kt], acc, 0, 0, 0);
            #pragma unroll
            for (int kt = 0; kt < 4; ++kt)
                acc = __builtin_amdgcn_mfma_f32_16x16x32_f16(al[kt], Bh[nt][kt], acc, 0, 0, 0);
            #pragma unroll
            for (int kt = 0; kt < 4; ++kt)
                acc = __builtin_amdgcn_mfma_f32_16x16x32_f16(ah[kt], Bl[nt][kt], acc, 0, 0, 0);
            float n2v = n2s[nt*16 + lr][pp];
            float cm_ = -3.4e38f;
            #pragma unroll
            for (int i = 0; i < 4; ++i) {
                float cv = acc[i] / (n1v[i] * n2v);
                rmax[i] = fmaxf(rmax[i], cv);
                cm_ = fmaxf(cm_, cv);
            }
            cmx[nt] = cm_;
        }
        #pragma unroll
        for (int msk = 1; msk < 16; msk <<= 1)
            #pragma unroll
            for (int i = 0; i < 4; ++i) rmax[i] = fmaxf(rmax[i], __shfl_xor(rmax[i], msk));
        if (lr == 0) {
            #pragma unroll
            for (int i = 0; i < 4; ++i)
                mp[((size_t)b*64 + w*16 + lc*4 + i)*160 + col] = rmax[i];
        }
        #pragma unroll
        for (int msk = 16; msk < 64; msk <<= 1)
            #pragma unroll
            for (int nt = 0; nt < 4; ++nt) cmx[nt] = fmaxf(cmx[nt], __shfl_xor(cmx[nt], msk));
        if (lc == 0) {
            #pragma unroll
            for (int nt = 0; nt < 4; ++nt) cpart[w][nt*16 + lr] = cmx[nt];
        }
        __syncthreads();
        if (tid < 64) {
            float mv = fmaxf(fmaxf(cpart[0][tid], cpart[1][tid]),
                             fmaxf(cpart[2][tid], cpart[3][tid]));
            mq[((size_t)b*64 + tid)*160 + col] = mv;
        }
        __syncthreads();
    }
}

// ---------------- final FC ----------------
__global__ void k_fc(const float* __restrict__ xcat,
                     const float* __restrict__ fc1W, const float* __restrict__ fc1b,
                     const float* __restrict__ fc2W, const float* __restrict__ fc2b,
                     float* __restrict__ out) {
    int b = blockIdx.x;
    int tid = threadIdx.x;   // 256
    __shared__ float y[256];
    const float* x = xcat + (size_t)b*512;
    float acc = fc1b[tid];
    #pragma unroll 8
    for (int k4 = 0; k4 < 128; ++k4) {
        float4 wv = *(const float4*)&fc1W[(size_t)tid*512 + k4*4];
        float4 xv = *(const float4*)&x[k4*4];
        acc += wv.x*xv.x + wv.y*xv.y + wv.z*xv.z + wv.w*xv.w;
    }
    y[tid] = tanhf(acc);
    __syncthreads();
    if (tid < 2) {
        float o = fc2b[tid];
        for (int k = 0; k < 256; ++k) o += y[k]*fc2W[tid*256 + k];
        out[b*2 + tid] = o;
    }
}

extern "C" void kernel_launch(void* const* d_in, const int* in_sizes, int n_in,
                              void* d_out, int out_size, void* d_ws, size_t ws_size,
                              hipStream_t stream) {
    (void)in_sizes; (void)n_in; (void)out_size; (void)ws_size;
    const int* idxA  = (const int*)d_in[0];
    const int* idxB  = (const int*)d_in[1];
    const int* cidxA = (const int*)d_in[2];
    const int* cidxB = (const int*)d_in[3];
    const float* wemb = (const float*)d_in[4];
    const float* cemb = (const float*)d_in[5];
    const float* cWih = (const float*)d_in[6];
    const float* cWhh = (const float*)d_in[7];
    const float* cb   = (const float*)d_in[8];
    const float* xWf = (const float*)d_in[9];
    const float* xUf = (const float*)d_in[10];
    const float* xbf = (const float*)d_in[11];
    const float* xWb = (const float*)d_in[12];
    const float* xUb = (const float*)d_in[13];
    const float* xbb = (const float*)d_in[14];
    const float* aWf = (const float*)d_in[15];
    const float* aUf = (const float*)d_in[16];
    const float* abf = (const float*)d_in[17];
    const float* aWb = (const float*)d_in[18];
    const float* aUb = (const float*)d_in[19];
    const float* abb = (const float*)d_in[20];
    const float* mpmw = (const float*)d_in[21];
    const float* fc1W = (const float*)d_in[22];
    const float* fc1b = (const float*)d_in[23];
    const float* fc2W = (const float*)d_in[24];
    const float* fc2b = (const float*)d_in[25];
    float* out = (float*)d_out;

    float* ws = (float*)d_ws;
    float* xw0 = ws; ws += (size_t)4096*512;
    float* xw1 = ws; ws += (size_t)4096*512;
    float* xw2 = ws; ws += (size_t)4096*512;
    float* xw3 = ws; ws += (size_t)4096*512;
    float* pfw = ws; ws += (size_t)4096*128;
    float* pbw = ws; ws += (size_t)4096*128;
    float* qfw = ws; ws += (size_t)4096*128;
    float* qbw = ws; ws += (size_t)4096*128;
    float* cmf = ws; ws += (size_t)64*64*64;
    float* cmb = ws; ws += (size_t)64*64*64;
    float* mp  = ws; ws += (size_t)4096*160;
    float* mq  = ws; ws += (size_t)4096*160;
    float* xcat = ws; ws += (size_t)64*512;
    unsigned short* Xaug = (unsigned short*)ws; ws += (size_t)8192*1152/2;   // bf16 [8192][1152]
    unsigned short* Wfa  = (unsigned short*)ws; ws += (size_t)512*1152/2;
    unsigned short* Wba  = (unsigned short*)ws; ws += (size_t)512*1152/2;
    unsigned short* WihC = (unsigned short*)ws; ws += (size_t)256*192/2;
    unsigned short* WhhC = (unsigned short*)ws; ws += (size_t)256*192/2;

    // 0. char LSTM weight conversions
    k_conv<<<256, 128, 0, stream>>>(cWih, WihC, 64, 64, 1);
    k_conv<<<256, 128, 0, stream>>>(cWhh, WhhC, 64, 64, 1);
    // 1. word embedding gather -> Xaug (split-bf16), zero-pads cols 300..383
    k_embed_word<<<8192, 128, 0, stream>>>(idxA, idxB, wemb, Xaug);
    // 2. char LSTM via MFMA -> Xaug cols 300..363 (split-bf16)
    k_char_mfma<<<256, 256, 0, stream>>>(cidxA, cidxB, cemb, WihC, WhhC, cb, Xaug);
    // 3. ctx weight conversions
    k_conv<<<512, 128, 0, stream>>>(xWf, Wfa, 364, 384, 1);
    k_conv<<<512, 128, 0, stream>>>(xWb, Wba, 364, 384, 1);
    // 4. ctx input projections via MFMA (4 scans: A-f, B-f, A-b, B-b)
    MfArgs cx;
    cx.X = Xaug;
    cx.W[0]=Wfa; cx.W[1]=Wfa; cx.W[2]=Wba; cx.W[3]=Wba;
    cx.bias[0]=xbf; cx.bias[1]=xbf; cx.bias[2]=xbb; cx.bias[3]=xbb;
    cx.out[0]=xw0; cx.out[1]=xw1; cx.out[2]=xw2; cx.out[3]=xw3;
    cx.flip[0]=0; cx.flip[1]=0; cx.flip[2]=1; cx.flip[3]=1;
    cx.rowBase[0]=0; cx.rowBase[1]=4096; cx.rowBase[2]=0; cx.rowBase[3]=4096;
    cx.Kaug = 1152;
    k_xw_mfma<<<dim3(32, 4, 4), 256, 0, stream>>>(cx);
    // 5. ctx recurrences (1024-thread split-K scalar scan, v_pk_fma_f32)
    ScanArgs cs;
    cs.xw[0]=xw0; cs.xw[1]=xw1; cs.xw[2]=xw2; cs.xw[3]=xw3;
    cs.whh[0]=xUf; cs.whh[1]=xUf; cs.whh[2]=xUb; cs.whh[3]=xUb;
    cs.out[0]=pfw; cs.out[1]=qfw; cs.out[2]=pbw; cs.out[3]=qbw;
    cs.flipOut[0]=0; cs.flipOut[1]=0; cs.flipOut[2]=1; cs.flipOut[3]=1;
    cs.writeAll = 1; cs.outStride = 0;
    k_lstm_scan<<<dim3(64, 4), 1024, 0, stream>>>(cs);
    // 6. cosine matrices (p vs q), fw and bw
    k_cos_matrix<<<dim3(64, 2), 256, 0, stream>>>(pfw, pbw, qfw, qbw, cmf, cmb);
    // 7. full / attentive / max-attentive parts for mp and mq
    k_full_att<<<dim3(64, 2, 2), 512, 0, stream>>>(pfw, pbw, qfw, qbw, cmf, cmb, mpmw, mp, mq);
    // 8. max-pool parts via MFMA (row-max -> mp, col-max -> mq)
    k_maxpool_mfma<<<dim3(64, 2, 2), 256, 0, stream>>>(pfw, pbw, qfw, qbw, mpmw, mp, mq);
    // 9. convert agg inputs/weights (reuse Xaug/Wfa/Wba buffers; Kaug=480)
    k_conv<<<4096, 128, 0, stream>>>(mp, Xaug, 160, 160, 0);
    k_conv<<<4096, 128, 0, stream>>>(mq, Xaug + (size_t)4096*480, 160, 160, 0);
    k_conv<<<512, 128, 0, stream>>>(aWf, Wfa, 160, 160, 1);
    k_conv<<<512, 128, 0, stream>>>(aWb, Wba, 160, 160, 1);
    // 10. agg input projections via MFMA
    MfArgs ax;
    ax.X = Xaug;
    ax.W[0]=Wfa; ax.W[1]=Wfa; ax.W[2]=Wba; ax.W[3]=Wba;
    ax.bias[0]=abf; ax.bias[1]=abf; ax.bias[2]=abb; ax.bias[3]=abb;
    ax.out[0]=xw0; ax.out[1]=xw1; ax.out[2]=xw2; ax.out[3]=xw3;
    ax.flip[0]=0; ax.flip[1]=0; ax.flip[2]=1; ax.flip[3]=1;
    ax.rowBase[0]=0; ax.rowBase[1]=4096; ax.rowBase[2]=0; ax.rowBase[3]=4096;
    ax.Kaug = 480;
    k_xw_mfma<<<dim3(32, 4, 4), 256, 0, stream>>>(ax);
    // 11. agg recurrences, final hidden only -> xcat [64][512]
    ScanArgs as;
    as.xw[0]=xw0; as.xw[1]=xw1; as.xw[2]=xw2; as.xw[3]=xw3;
    as.whh[0]=aUf; as.whh[1]=aUf; as.whh[2]=aUb; as.whh[3]=aUb;
    as.out[0]=xcat+0; as.out[1]=xcat+256; as.out[2]=xcat+128; as.out[3]=xcat+384;
    as.flipOut[0]=0; as.flipOut[1]=0; as.flipOut[2]=0; as.flipOut[3]=0;
    as.writeAll = 0; as.outStride = 512;
    k_lstm_scan<<<dim3(64, 4), 1024, 0, stream>>>(as);
    // 12. FC head
    k_fc<<<64, 256, 0, stream>>>(xcat, fc1W, fc1b, fc2W, fc2b, out);
}

// Round 14
// 366.121 us; speedup vs baseline: 3.6803x; 1.0078x over previous
//
#include <hip/hip_runtime.h>

#define EPS 1e-6f

typedef __attribute__((ext_vector_type(8))) short short8;
typedef __attribute__((ext_vector_type(8))) _Float16 half8;
typedef __attribute__((ext_vector_type(4))) float floatx4;
typedef __attribute__((ext_vector_type(2))) float floatx2;

struct ScanArgs {
    const float* xw[4];
    const float* whh[4];
    float* out[4];
    int flipOut[4];
    int writeAll;
    int outStride;
};

struct MfArgs {
    const unsigned short* X;        // [8192][Kaug] augmented bf16
    const unsigned short* W[4];     // [512][Kaug] augmented bf16
    const float* bias[4];
    float* out[4];                  // [4096][512] fp32
    int flip[4];
    int rowBase[4];
    int Kaug;
};

__device__ __forceinline__ float fsig(float x) { return 1.0f / (1.0f + __expf(-x)); }
__device__ __forceinline__ float tanh_fast(float x) {
    float e = __expf(2.f * x);
    return 1.f - 2.f / (e + 1.f);
}
__device__ __forceinline__ unsigned short f2bf(float x) {
    unsigned u = __float_as_uint(x);
    return (unsigned short)((u + 0x7fffu + ((u >> 16) & 1u)) >> 16);
}
__device__ __forceinline__ void split8_bf(const float* p, short8& hi, short8& lo) {
    #pragma unroll
    for (int e = 0; e < 8; ++e) {
        unsigned short h = f2bf(p[e]);
        float hf = __uint_as_float((unsigned)h << 16);
        hi[e] = (short)h;
        lo[e] = (short)f2bf(p[e] - hf);
    }
}
__device__ __forceinline__ void split8_f16(const float* p, half8& hi, half8& lo) {
    #pragma unroll
    for (int e = 0; e < 8; ++e) {
        _Float16 h = (_Float16)p[e];
        hi[e] = h;
        lo[e] = (_Float16)(p[e] - (float)h);
    }
}
__device__ __forceinline__ floatx2 pk_fma(floatx2 a, floatx2 b, floatx2 c) {
    floatx2 d;
    asm("v_pk_fma_f32 %0, %1, %2, %3" : "=v"(d) : "v"(a), "v"(b), "v"(c));
    return d;
}
// write one value into agg Xaug row (stride 480: [hi 160 | lo 160 | hi 160])
__device__ __forceinline__ void storeAug(unsigned short* d, int col, float v) {
    unsigned short h = f2bf(v);
    float hf = __uint_as_float((unsigned)h << 16);
    unsigned short l = f2bf(v - hf);
    d[col] = h; d[160 + col] = l; d[320 + col] = h;
}

// ---------------- word embedding gather -> split-bf16 Xaug directly ----------------
__global__ void k_embed_word(const int* __restrict__ idxA, const int* __restrict__ idxB,
                             const float* __restrict__ emb,
                             unsigned short* __restrict__ Xaug) {
    int row = blockIdx.x;              // 0..8191 (A rows 0..4095, B rows 4096..8191)
    const int* idx = (row < 4096) ? idxA : idxB;
    int r = row & 4095;
    size_t e = (size_t)idx[r];
    const float* src = emb + e * 300;
    unsigned short* d = Xaug + (size_t)row * 1152;
    for (int k = threadIdx.x; k < 384; k += blockDim.x) {
        float x = (k < 300) ? src[k] : 0.f;
        unsigned short hr = f2bf(x);
        float hif = __uint_as_float((unsigned)hr << 16);
        unsigned short lr2 = f2bf(x - hif);
        d[k]       = hr;
        d[384 + k] = lr2;
        d[768 + k] = hr;
    }
}

// ---------------- fp32 -> augmented split-bf16 (X: [hi|lo|hi], W: [hi|hi|lo]) ------------
__global__ void k_conv(const float* __restrict__ src, unsigned short* __restrict__ dst,
                       int K, int Ksec, int isW) {
    int row = blockIdx.x;
    const float* s = src + (size_t)row * K;
    unsigned short* d = dst + (size_t)row * (3 * Ksec);
    int o1 = (isW ? 2 : 1) * Ksec;   // where lo goes
    int o2 = (isW ? 1 : 2) * Ksec;   // where second hi goes
    for (int k = threadIdx.x; k < Ksec; k += blockDim.x) {
        float x = (k < K) ? s[k] : 0.f;
        unsigned short hr = f2bf(x);
        float hif = __uint_as_float((unsigned)hr << 16);
        unsigned short lr2 = f2bf(x - hif);
        d[k]      = hr;
        d[o1 + k] = lr2;
        d[o2 + k] = hr;
    }
}

// ---------------- char LSTM via MFMA: 32 seqs/block -> split-bf16 Xaug cols 300..363 -----
__global__ __launch_bounds__(256, 1)
void k_char_mfma(const int* __restrict__ cidxA, const int* __restrict__ cidxB,
                 const float* __restrict__ emb,
                 const unsigned short* __restrict__ WihA, const unsigned short* __restrict__ WhhA,
                 const float* __restrict__ bias,
                 unsigned short* __restrict__ Xaug) {
    __shared__ __align__(16) float xs[32][68];
    __shared__ __align__(16) float hs[32][68];
    int tid = threadIdx.x;
    int w = tid >> 6, l = tid & 63, lr = l & 15, lc = l >> 4;
    int j = w * 16 + lr;              // h-dim column this lane covers
    short8 wih[4][6], whh[4][6];
    #pragma unroll
    for (int g = 0; g < 4; ++g)
        #pragma unroll
        for (int kt = 0; kt < 6; ++kt) {
            wih[g][kt] = *(const short8*)&WihA[(size_t)(g*64 + j)*192 + kt*32 + lc*8];
            whh[g][kt] = *(const short8*)&WhhA[(size_t)(g*64 + j)*192 + kt*32 + lc*8];
        }
    float bg[4];
    #pragma unroll
    for (int g = 0; g < 4; ++g) bg[g] = bias[g*64 + j];
    int seq0 = blockIdx.x * 32;
    for (int m = tid; m < 32*68; m += 256) (&hs[0][0])[m] = 0.f;
    float cst[2][4] = {};
    float hlast[2][4];
    __syncthreads();
    for (int t = 0; t < 8; ++t) {
        {
            int s = tid >> 3, ch = tid & 7;
            int sq = seq0 + s;
            const int* ci = (sq < 4096) ? cidxA : cidxB;
            int e = ci[(sq & 4095)*8 + t];
            float4 v0 = *(const float4*)&emb[(size_t)e*64 + ch*8];
            float4 v1 = *(const float4*)&emb[(size_t)e*64 + ch*8 + 4];
            *(float4*)&xs[s][ch*8] = v0;
            *(float4*)&xs[s][ch*8 + 4] = v1;
        }
        short8 hhi[2][2], hlo[2][2];
        if (t > 0) {
            #pragma unroll
            for (int mt = 0; mt < 2; ++mt)
                #pragma unroll
                for (int kt = 0; kt < 2; ++kt) {
                    float tmp[8];
                    *(float4*)&tmp[0] = *(const float4*)&hs[mt*16 + lr][kt*32 + lc*8];
                    *(float4*)&tmp[4] = *(const float4*)&hs[mt*16 + lr][kt*32 + lc*8 + 4];
                    split8_bf(tmp, hhi[mt][kt], hlo[mt][kt]);
                }
        }
        __syncthreads();   // A: xs staged; hs reads done
        short8 xhi[2][2], xlo[2][2];
        #pragma unroll
        for (int mt = 0; mt < 2; ++mt)
            #pragma unroll
            for (int kt = 0; kt < 2; ++kt) {
                float tmp[8];
                *(float4*)&tmp[0] = *(const float4*)&xs[mt*16 + lr][kt*32 + lc*8];
                *(float4*)&tmp[4] = *(const float4*)&xs[mt*16 + lr][kt*32 + lc*8 + 4];
                split8_bf(tmp, xhi[mt][kt], xlo[mt][kt]);
            }
        #pragma unroll
        for (int mt = 0; mt < 2; ++mt)
            #pragma unroll
            for (int g = 0; g < 4; ++g) {
                floatx4 a = {bg[g], bg[g], bg[g], bg[g]};
                a = __builtin_amdgcn_mfma_f32_16x16x32_bf16(xhi[mt][0], wih[g][0], a, 0, 0, 0);
                a = __builtin_amdgcn_mfma_f32_16x16x32_bf16(xhi[mt][1], wih[g][1], a, 0, 0, 0);
                a = __builtin_amdgcn_mfma_f32_16x16x32_bf16(xlo[mt][0], wih[g][2], a, 0, 0, 0);
                a = __builtin_amdgcn_mfma_f32_16x16x32_bf16(xlo[mt][1], wih[g][3], a, 0, 0, 0);
                a = __builtin_amdgcn_mfma_f32_16x16x32_bf16(xhi[mt][0], wih[g][4], a, 0, 0, 0);
                a = __builtin_amdgcn_mfma_f32_16x16x32_bf16(xhi[mt][1], wih[g][5], a, 0, 0, 0);
                if (t > 0) {
                    a = __builtin_amdgcn_mfma_f32_16x16x32_bf16(hhi[mt][0], whh[g][0], a, 0, 0, 0);
                    a = __builtin_amdgcn_mfma_f32_16x16x32_bf16(hhi[mt][1], whh[g][1], a, 0, 0, 0);
                    a = __builtin_amdgcn_mfma_f32_16x16x32_bf16(hlo[mt][0], whh[g][2], a, 0, 0, 0);
                    a = __builtin_amdgcn_mfma_f32_16x16x32_bf16(hlo[mt][1], whh[g][3], a, 0, 0, 0);
                    a = __builtin_amdgcn_mfma_f32_16x16x32_bf16(hhi[mt][0], whh[g][4], a, 0, 0, 0);
                    a = __builtin_amdgcn_mfma_f32_16x16x32_bf16(hhi[mt][1], whh[g][5], a, 0, 0, 0);
                }
                if (g == 0) { hlast[mt][0] = a[0]; hlast[mt][1] = a[1]; hlast[mt][2] = a[2]; hlast[mt][3] = a[3]; }
                else if (g == 1) {
                    #pragma unroll
                    for (int i = 0; i < 4; ++i) cst[mt][i] = fsig(a[i]) * cst[mt][i];
                } else if (g == 2) {
                    #pragma unroll
                    for (int i = 0; i < 4; ++i) cst[mt][i] += fsig(hlast[mt][i]) * tanh_fast(a[i]);
                } else {
                    #pragma unroll
                    for (int i = 0; i < 4; ++i) {
                        float h = fsig(a[i]) * tanh_fast(cst[mt][i]);
                        hlast[mt][i] = h;
                        hs[mt*16 + lc*4 + i][j] = h;
                    }
                }
            }
        __syncthreads();   // B: hs writes visible; xs reads done
    }
    #pragma unroll
    for (int mt = 0; mt < 2; ++mt)
        #pragma unroll
        for (int i = 0; i < 4; ++i) {
            int s = mt*16 + lc*4 + i;
            int sq = seq0 + s;                     // global Xaug row
            unsigned short* d = Xaug + (size_t)sq * 1152;
            float h = hlast[mt][i];
            unsigned short hh = f2bf(h);
            float hf = __uint_as_float((unsigned)hh << 16);
            unsigned short hl = f2bf(h - hf);
            int k = 300 + j;
            d[k]       = hh;
            d[384 + k] = hl;
            d[768 + k] = hh;
        }
}

// ---------------- MFMA input-projection GEMM: out[row][n] = bias[n] + sum_k X[srow][k]*W[n][k]
__global__ __launch_bounds__(256, 2)
void k_xw_mfma(MfArgs a) {
    int scan = blockIdx.z;
    const unsigned short* X = a.X;
    const unsigned short* W = a.W[scan];
    const float* bias = a.bias[scan];
    float* out = a.out[scan];
    int flip = a.flip[scan];
    int rowBase = a.rowBase[scan];
    int Kaug = a.Kaug;
    int m0 = blockIdx.x * 128;
    int n0 = blockIdx.y * 128;
    __shared__ __align__(16) unsigned short As[128][40];
    __shared__ __align__(16) unsigned short Bs[128][40];
    int tid = threadIdx.x;
    int wv = tid >> 6, lane = tid & 63;
    int lr = lane & 15, lc = lane >> 4;

    floatx4 acc[2][8];
    #pragma unroll
    for (int f = 0; f < 2; ++f)
        #pragma unroll
        for (int g = 0; g < 8; ++g)
            acc[f][g] = (floatx4){0.f, 0.f, 0.f, 0.f};

    int r0 = m0 + (tid >> 2);
    int r1 = r0 + 64;
    int sr0 = rowBase + (flip ? ((r0 & ~63) | (63 - (r0 & 63))) : r0);
    int sr1 = rowBase + (flip ? ((r1 & ~63) | (63 - (r1 & 63))) : r1);
    size_t asrc0 = (size_t)sr0 * Kaug + (tid & 3) * 8;
    size_t asrc1 = (size_t)sr1 * Kaug + (tid & 3) * 8;
    size_t bsrc0 = (size_t)(n0 + (tid >> 2)) * Kaug + (tid & 3) * 8;
    size_t bsrc1 = (size_t)(n0 + (tid >> 2) + 64) * Kaug + (tid & 3) * 8;
    int swrow = tid >> 2, swcol = (tid & 3) * 8;

    for (int k0 = 0; k0 < Kaug; k0 += 32) {
        short8 a0 = *(const short8*)(X + asrc0 + k0);
        short8 a1 = *(const short8*)(X + asrc1 + k0);
        short8 b0 = *(const short8*)(W + bsrc0 + k0);
        short8 b1 = *(const short8*)(W + bsrc1 + k0);
        __syncthreads();
        *(short8*)&As[swrow][swcol]      = a0;
        *(short8*)&As[swrow + 64][swcol] = a1;
        *(short8*)&Bs[swrow][swcol]      = b0;
        *(short8*)&Bs[swrow + 64][swcol] = b1;
        __syncthreads();
        short8 af0 = *(const short8*)&As[wv*32 + lr][lc*8];
        short8 af1 = *(const short8*)&As[wv*32 + 16 + lr][lc*8];
        #pragma unroll
        for (int g = 0; g < 8; ++g) {
            short8 bf = *(const short8*)&Bs[g*16 + lr][lc*8];
            acc[0][g] = __builtin_amdgcn_mfma_f32_16x16x32_bf16(af0, bf, acc[0][g], 0, 0, 0);
            acc[1][g] = __builtin_amdgcn_mfma_f32_16x16x32_bf16(af1, bf, acc[1][g], 0, 0, 0);
        }
    }

    #pragma unroll
    for (int f = 0; f < 2; ++f) {
        int row = m0 + wv*32 + f*16 + lc*4;
        #pragma unroll
        for (int g = 0; g < 8; ++g) {
            int col = n0 + g*16 + lr;
            float bv = bias[col];
            #pragma unroll
            for (int i = 0; i < 4; ++i)
                out[(size_t)(row + i)*512 + col] = acc[f][g][i] + bv;
        }
    }
}

// ---------------- LSTM recurrence: 1024 threads, split-K, packed-fp32 FMA (r9 version) ----
__global__ __launch_bounds__(1024, 4)
void k_lstm_scan(ScanArgs a) {
    int b = blockIdx.x;
    int scan = blockIdx.y;
    int tid = threadIdx.x;
    int p = tid >> 9;                  // K-half 0/1
    int g = tid & 511;                 // gate row
    __shared__ __align__(16) float h_lds[128];
    __shared__ float gpart[2][512];
    const float* W = a.whh[scan] + (size_t)g*128 + p*64;
    floatx2 w2[32];
    #pragma unroll
    for (int k = 0; k < 32; ++k) w2[k] = *(const floatx2*)&W[k*2];
    const float* xw = a.xw[scan] + (size_t)b*64*512;
    float* outp = a.out[scan];
    int flip = a.flipOut[scan];
    int wAll = a.writeAll;
    float c = 0.f;
    if (tid < 128) h_lds[tid] = 0.f;
    __syncthreads();
    const float* hb = &h_lds[p*64];
    float xwc = (p == 0) ? xw[g] : 0.f;
    for (int t = 0; t < 64; ++t) {
        float xwn = 0.f;
        if (p == 0 && t < 63) xwn = xw[(size_t)(t+1)*512 + g];
        floatx2 a0 = {0.f,0.f}, a1 = {0.f,0.f}, a2 = {0.f,0.f}, a3 = {0.f,0.f};
        #pragma unroll
        for (int kk = 0; kk < 8; ++kk) {
            floatx4 u = *(const floatx4*)&hb[kk*8];
            floatx4 v = *(const floatx4*)&hb[kk*8 + 4];
            a0 = pk_fma(w2[kk*4+0], __builtin_shufflevector(u, u, 0, 1), a0);
            a1 = pk_fma(w2[kk*4+1], __builtin_shufflevector(u, u, 2, 3), a1);
            a2 = pk_fma(w2[kk*4+2], __builtin_shufflevector(v, v, 0, 1), a2);
            a3 = pk_fma(w2[kk*4+3], __builtin_shufflevector(v, v, 2, 3), a3);
        }
        float s = ((a0.x + a0.y) + (a1.x + a1.y)) + ((a2.x + a2.y) + (a3.x + a3.y));
        gpart[p][g] = xwc + s;
        __syncthreads();
        if (tid < 128) {
            float gi = gpart[0][tid]       + gpart[1][tid];
            float gf = gpart[0][128 + tid] + gpart[1][128 + tid];
            float gg = gpart[0][256 + tid] + gpart[1][256 + tid];
            float go = gpart[0][384 + tid] + gpart[1][384 + tid];
            c = fsig(gf)*c + fsig(gi)*tanhf(gg);
            float h = fsig(go)*tanhf(c);
            h_lds[tid] = h;
            if (wAll) {
                int tout = flip ? (63 - t) : t;
                outp[((size_t)b*64 + tout)*128 + tid] = h;
            }
        }
        __syncthreads();
        xwc = xwn;
    }
    if (!wAll && tid < 128)
        outp[(size_t)b * a.outStride + tid] = h_lds[tid];
}

// ---------------- cosine matrix cm[b][i][j] between p_dir and q_dir rows ----------------
__global__ __launch_bounds__(256, 1)
void k_cos_matrix(const float* __restrict__ pfw, const float* __restrict__ pbw,
                  const float* __restrict__ qfw, const float* __restrict__ qbw,
                  float* __restrict__ cmf, float* __restrict__ cmb) {
    int b = blockIdx.x, dir = blockIdx.y;
    const float* h1 = (dir ? pbw : pfw) + (size_t)b*8192;
    const float* h2 = (dir ? qbw : qfw) + (size_t)b*8192;
    float* cm = (dir ? cmb : cmf) + (size_t)b*4096;
    __shared__ __align__(16) float A[64][132];
    __shared__ __align__(16) float Bt[64][132];
    __shared__ float n1[64], n2[64];
    int tid = threadIdx.x;
    for (int m = tid; m < 8192; m += 256) {
        int r = m >> 7, d = m & 127;
        A[r][d] = h1[m];
        Bt[r][d] = h2[m];
    }
    __syncthreads();
    if (tid < 128) {
        const float* row = (tid < 64) ? &A[tid][0] : &Bt[tid-64][0];
        float s = 0.f;
        #pragma unroll
        for (int k4 = 0; k4 < 32; ++k4) {
            float4 v = *(const float4*)&row[k4*4];
            s += v.x*v.x + v.y*v.y + v.z*v.z + v.w*v.w;
        }
        float nv = sqrtf(fmaxf(s, EPS));
        if (tid < 64) n1[tid] = nv; else n2[tid-64] = nv;
    }
    __syncthreads();
    int tx = tid & 15, ty = tid >> 4;
    float acc[4][4] = {};
    #pragma unroll
    for (int k4 = 0; k4 < 32; ++k4) {
        float4 av[4], bv[4];
        #pragma unroll
        for (int i = 0; i < 4; ++i) av[i] = *(const float4*)&A[ty + i*16][k4*4];
        #pragma unroll
        for (int j = 0; j < 4; ++j) bv[j] = *(const float4*)&Bt[tx + j*16][k4*4];
        #pragma unroll
        for (int i = 0; i < 4; ++i)
            #pragma unroll
            for (int j = 0; j < 4; ++j)
                acc[i][j] += av[i].x*bv[j].x + av[i].y*bv[j].y + av[i].z*bv[j].z + av[i].w*bv[j].w;
    }
    #pragma unroll
    for (int i = 0; i < 4; ++i) {
        int r = ty + i*16;
        #pragma unroll
        for (int j = 0; j < 4; ++j) {
            int c2 = tx + j*16;
            cm[r*64 + c2] = acc[i][j] / (n1[r]*n2[c2]);
        }
    }
}

// ---------------- full / attentive / max-attentive parts -> split-bf16 agg Xaug ----------
__global__ __launch_bounds__(512, 2)
void k_full_att(const float* __restrict__ pfw, const float* __restrict__ pbw,
                const float* __restrict__ qfw, const float* __restrict__ qbw,
                const float* __restrict__ cmf, const float* __restrict__ cmb,
                const float* __restrict__ mpmw,
                unsigned short* __restrict__ Xagg) {
    int b = blockIdx.x, dir = blockIdx.y, which = blockIdx.z;
    const float* pd = (dir ? pbw : pfw) + (size_t)b*8192;
    const float* qd = (dir ? qbw : qfw) + (size_t)b*8192;
    const float* h1g = which ? qd : pd;
    const float* h2g = which ? pd : qd;
    const float* cmsrc = (dir ? cmb : cmf) + (size_t)b*4096;
    __shared__ __align__(16) float h2s[64][132];
    __shared__ float cms[64][68];
    __shared__ __align__(16) float wl[3*20*128];
    int tid = threadIdx.x;
    for (int m = tid; m < 8192; m += 512) {
        int r = m >> 7, d = m & 127;
        h2s[r][d] = h2g[m];
    }
    for (int m = tid; m < 4096; m += 512) {
        int l = m >> 6, j = m & 63;
        cms[l][j] = which ? cmsrc[j*64 + l] : cmsrc[m];
    }
    for (int m = tid; m < 2560; m += 512) {
        wl[m]        = mpmw[(size_t)(0+dir)*2560 + m];
        wl[2560 + m] = mpmw[(size_t)(2+dir)*2560 + m];
        wl[5120 + m] = mpmw[(size_t)(4+dir)*2560 + m];
    }
    __syncthreads();
    int l = tid >> 3, r = tid & 7;
    int d0 = r * 16;
    float h1d[16];
    #pragma unroll
    for (int q4 = 0; q4 < 4; ++q4) {
        float4 v = *(const float4*)&h1g[l*128 + d0 + q4*4];
        h1d[q4*4+0]=v.x; h1d[q4*4+1]=v.y; h1d[q4*4+2]=v.z; h1d[q4*4+3]=v.w;
    }
    float rsum = 0.f, bv = -3.4e38f; int bj = 64;
    for (int jj = 0; jj < 8; ++jj) {
        int j = r*8 + jj;
        float cv = cms[l][j];
        rsum += cv;
        if (cv > bv) { bv = cv; bj = j; }
    }
    #pragma unroll
    for (int m = 1; m < 8; m <<= 1) rsum += __shfl_xor(rsum, m, 8);
    #pragma unroll
    for (int m = 1; m < 8; m <<= 1) {
        float ov = __shfl_xor(bv, m, 8);
        int oj = __shfl_xor(bj, m, 8);
        if (ov > bv || (ov == bv && oj < bj)) { bv = ov; bj = oj; }
    }
    float att[16];
    #pragma unroll
    for (int dd = 0; dd < 16; ++dd) att[dd] = 0.f;
    for (int j = 0; j < 64; ++j) {
        float cv = cms[l][j];
        #pragma unroll
        for (int q4 = 0; q4 < 4; ++q4) {
            float4 hv = *(const float4*)&h2s[j][d0 + q4*4];
            att[q4*4+0] += cv*hv.x; att[q4*4+1] += cv*hv.y;
            att[q4*4+2] += cv*hv.z; att[q4*4+3] += cv*hv.w;
        }
    }
    float rinv = 1.f / (rsum + EPS);
    #pragma unroll
    for (int dd = 0; dd < 16; ++dd) att[dd] *= rinv;
    float mvd[16], h2l[16];
    #pragma unroll
    for (int q4 = 0; q4 < 4; ++q4) {
        float4 v = *(const float4*)&h2s[bj][d0 + q4*4];
        mvd[q4*4+0]=v.x; mvd[q4*4+1]=v.y; mvd[q4*4+2]=v.z; mvd[q4*4+3]=v.w;
        float4 u = *(const float4*)&h2s[63][d0 + q4*4];
        h2l[q4*4+0]=u.x; h2l[q4*4+1]=u.y; h2l[q4*4+2]=u.z; h2l[q4*4+3]=u.w;
    }
    unsigned short* drow = Xagg + (size_t)(which*4096 + b*64 + l) * 480;
    for (int pp = 0; pp < 20; ++pp) {
        const float* wf = &wl[pp*128 + d0];
        const float* wa = &wl[2560 + pp*128 + d0];
        const float* wm = &wl[5120 + pp*128 + d0];
        float fn=0,f1=0,f2=0, an=0,a1=0,a2=0, mn=0,m1=0,m2=0;
        #pragma unroll
        for (int dd = 0; dd < 16; ++dd) {
            float wfv = wf[dd], wav = wa[dd], wmv = wm[dd];
            float x1 = h1d[dd]*wfv, x2 = h2l[dd]*wfv;
            fn += x1*x2; f1 += x1*x1; f2 += x2*x2;
            float y1 = h1d[dd]*wav, y2 = att[dd]*wav;
            an += y1*y2; a1 += y1*y1; a2 += y2*y2;
            float z1 = h1d[dd]*wmv, z2 = mvd[dd]*wmv;
            mn += z1*z2; m1 += z1*z1; m2 += z2*z2;
        }
        #pragma unroll
        for (int m = 1; m < 8; m <<= 1) {
            fn += __shfl_xor(fn,m,8); f1 += __shfl_xor(f1,m,8); f2 += __shfl_xor(f2,m,8);
            an += __shfl_xor(an,m,8); a1 += __shfl_xor(a1,m,8); a2 += __shfl_xor(a2,m,8);
            mn += __shfl_xor(mn,m,8); m1 += __shfl_xor(m1,m,8); m2 += __shfl_xor(m2,m,8);
        }
        if (r == 0) {
            storeAug(drow, (0+dir)*20 + pp, fn / sqrtf(fmaxf(f1,EPS)) / sqrtf(fmaxf(f2,EPS)));
            storeAug(drow, (2+dir)*20 + pp, an / sqrtf(fmaxf(a1,EPS)) / sqrtf(fmaxf(a2,EPS)));
            storeAug(drow, (4+dir)*20 + pp, mn / sqrtf(fmaxf(m1,EPS)) / sqrtf(fmaxf(m2,EPS)));
        }
    }
}

// ---------------- max-pool via split-f16 MFMA -> split-bf16 agg Xaug ----------------------
__global__ __launch_bounds__(256, 1)
void k_maxpool_mfma(const float* __restrict__ pfw, const float* __restrict__ pbw,
                    const float* __restrict__ qfw, const float* __restrict__ qbw,
                    const float* __restrict__ mpmw,
                    unsigned short* __restrict__ Xagg) {
    int b = blockIdx.x, dir = blockIdx.y, pph = blockIdx.z;
    const float* h1 = (dir ? pbw : pfw) + (size_t)b*8192;
    const float* h2 = (dir ? qbw : qfw) + (size_t)b*8192;
    __shared__ __align__(16) float h1s[64][132];
    __shared__ __align__(16) float h2s[64][132];
    __shared__ __align__(16) float w2s[32][132];
    __shared__ float n1s[64][25], n2s[64][25];
    __shared__ float cpart[4][68];
    int tid = threadIdx.x;
    int w = tid >> 6, l = tid & 63, lr = l & 15, lc = l >> 4;
    for (int m = tid; m < 8192; m += 256) {
        int r = m >> 7, d = m & 127;
        h1s[r][d] = h1[m];
        h2s[r][d] = h2[m];
    }
    for (int m = tid; m < 32*128; m += 256) {
        int r = m >> 7, d = m & 127;
        float v = (r < 20) ? mpmw[(size_t)((6+dir)*20 + r)*128 + d] : 0.f;
        w2s[r][d] = v * v;
    }
    __syncthreads();
    float a1[32], b1[32];
    #pragma unroll
    for (int kt = 0; kt < 4; ++kt) {
        *(float4*)&a1[kt*8]     = *(const float4*)&h1s[w*16 + lr][kt*32 + lc*8];
        *(float4*)&a1[kt*8 + 4] = *(const float4*)&h1s[w*16 + lr][kt*32 + lc*8 + 4];
        *(float4*)&b1[kt*8]     = *(const float4*)&h2s[w*16 + lr][kt*32 + lc*8];
        *(float4*)&b1[kt*8 + 4] = *(const float4*)&h2s[w*16 + lr][kt*32 + lc*8 + 4];
    }
    half8 Bh[4][4], Bl[4][4];
    #pragma unroll
    for (int nt = 0; nt < 4; ++nt)
        #pragma unroll
        for (int kt = 0; kt < 4; ++kt) {
            float tmp[8];
            *(float4*)&tmp[0] = *(const float4*)&h2s[nt*16 + lr][kt*32 + lc*8];
            *(float4*)&tmp[4] = *(const float4*)&h2s[nt*16 + lr][kt*32 + lc*8 + 4];
            split8_f16(tmp, Bh[nt][kt], Bl[nt][kt]);
        }
    {
        float sq[32];
        half8 s1h[4], s1l[4], s2h[4], s2l[4];
        #pragma unroll
        for (int kt = 0; kt < 4; ++kt) {
            #pragma unroll
            for (int e = 0; e < 8; ++e) sq[kt*8+e] = a1[kt*8+e]*a1[kt*8+e];
            split8_f16(&sq[kt*8], s1h[kt], s1l[kt]);
        }
        #pragma unroll
        for (int kt = 0; kt < 4; ++kt) {
            #pragma unroll
            for (int e = 0; e < 8; ++e) sq[kt*8+e] = b1[kt*8+e]*b1[kt*8+e];
            split8_f16(&sq[kt*8], s2h[kt], s2l[kt]);
        }
        half8 w2h[2][4], w2l[2][4];
        #pragma unroll
        for (int nt2 = 0; nt2 < 2; ++nt2)
            #pragma unroll
            for (int kt = 0; kt < 4; ++kt) {
                float tmp[8];
                *(float4*)&tmp[0] = *(const float4*)&w2s[nt2*16 + lr][kt*32 + lc*8];
                *(float4*)&tmp[4] = *(const float4*)&w2s[nt2*16 + lr][kt*32 + lc*8 + 4];
                split8_f16(tmp, w2h[nt2][kt], w2l[nt2][kt]);
            }
        #pragma unroll
        for (int nt2 = 0; nt2 < 2; ++nt2) {
            floatx4 na1 = {0.f,0.f,0.f,0.f}, na2 = {0.f,0.f,0.f,0.f};
            #pragma unroll
            for (int kt = 0; kt < 4; ++kt) {
                na1 = __builtin_amdgcn_mfma_f32_16x16x32_f16(s1h[kt], w2h[nt2][kt], na1, 0, 0, 0);
                na2 = __builtin_amdgcn_mfma_f32_16x16x32_f16(s2h[kt], w2h[nt2][kt], na2, 0, 0, 0);
            }
            #pragma unroll
            for (int kt = 0; kt < 4; ++kt) {
                na1 = __builtin_amdgcn_mfma_f32_16x16x32_f16(s1l[kt], w2h[nt2][kt], na1, 0, 0, 0);
                na2 = __builtin_amdgcn_mfma_f32_16x16x32_f16(s2l[kt], w2h[nt2][kt], na2, 0, 0, 0);
            }
            #pragma unroll
            for (int kt = 0; kt < 4; ++kt) {
                na1 = __builtin_amdgcn_mfma_f32_16x16x32_f16(s1h[kt], w2l[nt2][kt], na1, 0, 0, 0);
                na2 = __builtin_amdgcn_mfma_f32_16x16x32_f16(s2h[kt], w2l[nt2][kt], na2, 0, 0, 0);
            }
            #pragma unroll
            for (int i = 0; i < 4; ++i) {
                int row = w*16 + lc*4 + i;
                int c2 = nt2*16 + lr;
                if (c2 < 20) {
                    n1s[row][c2] = sqrtf(fmaxf(na1[i], EPS));
                    n2s[row][c2] = sqrtf(fmaxf(na2[i], EPS));
                }
            }
        }
    }
    __syncthreads();
    for (int pi = 0; pi < 10; ++pi) {
        int pp = pph*10 + pi;
        int col = (6+dir)*20 + pp;
        half8 ah[4], al[4];
        #pragma unroll
        for (int kt = 0; kt < 4; ++kt) {
            float wv[8], aw[8];
            *(float4*)&wv[0] = *(const float4*)&w2s[pp][kt*32 + lc*8];
            *(float4*)&wv[4] = *(const float4*)&w2s[pp][kt*32 + lc*8 + 4];
            #pragma unroll
            for (int e = 0; e < 8; ++e) aw[e] = a1[kt*8+e]*wv[e];
            split8_f16(aw, ah[kt], al[kt]);
        }
        float n1v[4];
        #pragma unroll
        for (int i = 0; i < 4; ++i) n1v[i] = n1s[w*16 + lc*4 + i][pp];
        float rmax[4] = {-3.4e38f, -3.4e38f, -3.4e38f, -3.4e38f};
        float cmx[4];
        #pragma unroll
        for (int nt = 0; nt < 4; ++nt) {
            floatx4 acc = {0.f,0.f,0.f,0.f};
            #pragma unroll
            for (int kt = 0; kt < 4; ++kt)
                acc = __builtin_amdgcn_mfma_f32_16x16x32_f16(ah[kt], Bh[nt][kt], acc, 0, 0, 0);
            #pragma unroll
            for (int kt = 0; kt < 4; ++kt)
                acc = __builtin_amdgcn_mfma_f32_16x16x32_f16(al[kt], Bh[nt][kt], acc, 0, 0, 0);
            #pragma unroll
            for (int kt = 0; kt < 4; ++kt)
                acc = __builtin_amdgcn_mfma_f32_16x16x32_f16(ah[kt], Bl[nt][kt], acc, 0, 0, 0);
            float n2v = n2s[nt*16 + lr][pp];
            float cm_ = -3.4e38f;
            #pragma unroll
            for (int i = 0; i < 4; ++i) {
                float cv = acc[i] / (n1v[i] * n2v);
                rmax[i] = fmaxf(rmax[i], cv);
                cm_ = fmaxf(cm_, cv);
            }
            cmx[nt] = cm_;
        }
        #pragma unroll
        for (int msk = 1; msk < 16; msk <<= 1)
            #pragma unroll
            for (int i = 0; i < 4; ++i) rmax[i] = fmaxf(rmax[i], __shfl_xor(rmax[i], msk));
        if (lr == 0) {
            #pragma unroll
            for (int i = 0; i < 4; ++i) {
                unsigned short* drow = Xagg + (size_t)(b*64 + w*16 + lc*4 + i) * 480;
                storeAug(drow, col, rmax[i]);
            }
        }
        #pragma unroll
        for (int msk = 16; msk < 64; msk <<= 1)
            #pragma unroll
            for (int nt = 0; nt < 4; ++nt) cmx[nt] = fmaxf(cmx[nt], __shfl_xor(cmx[nt], msk));
        if (lc == 0) {
            #pragma unroll
            for (int nt = 0; nt < 4; ++nt) cpart[w][nt*16 + lr] = cmx[nt];
        }
        __syncthreads();
        if (tid < 64) {
            float mv = fmaxf(fmaxf(cpart[0][tid], cpart[1][tid]),
                             fmaxf(cpart[2][tid], cpart[3][tid]));
            unsigned short* drow = Xagg + (size_t)(4096 + b*64 + tid) * 480;
            storeAug(drow, col, mv);
        }
        __syncthreads();
    }
}

// ---------------- final FC ----------------
__global__ void k_fc(const float* __restrict__ xcat,
                     const float* __restrict__ fc1W, const float* __restrict__ fc1b,
                     const float* __restrict__ fc2W, const float* __restrict__ fc2b,
                     float* __restrict__ out) {
    int b = blockIdx.x;
    int tid = threadIdx.x;   // 256
    __shared__ float y[256];
    const float* x = xcat + (size_t)b*512;
    float acc = fc1b[tid];
    #pragma unroll 8
    for (int k4 = 0; k4 < 128; ++k4) {
        float4 wv = *(const float4*)&fc1W[(size_t)tid*512 + k4*4];
        float4 xv = *(const float4*)&x[k4*4];
        acc += wv.x*xv.x + wv.y*xv.y + wv.z*xv.z + wv.w*xv.w;
    }
    y[tid] = tanhf(acc);
    __syncthreads();
    if (tid < 2) {
        float o = fc2b[tid];
        for (int k = 0; k < 256; ++k) o += y[k]*fc2W[tid*256 + k];
        out[b*2 + tid] = o;
    }
}

extern "C" void kernel_launch(void* const* d_in, const int* in_sizes, int n_in,
                              void* d_out, int out_size, void* d_ws, size_t ws_size,
                              hipStream_t stream) {
    (void)in_sizes; (void)n_in; (void)out_size; (void)ws_size;
    const int* idxA  = (const int*)d_in[0];
    const int* idxB  = (const int*)d_in[1];
    const int* cidxA = (const int*)d_in[2];
    const int* cidxB = (const int*)d_in[3];
    const float* wemb = (const float*)d_in[4];
    const float* cemb = (const float*)d_in[5];
    const float* cWih = (const float*)d_in[6];
    const float* cWhh = (const float*)d_in[7];
    const float* cb   = (const float*)d_in[8];
    const float* xWf = (const float*)d_in[9];
    const float* xUf = (const float*)d_in[10];
    const float* xbf = (const float*)d_in[11];
    const float* xWb = (const float*)d_in[12];
    const float* xUb = (const float*)d_in[13];
    const float* xbb = (const float*)d_in[14];
    const float* aWf = (const float*)d_in[15];
    const float* aUf = (const float*)d_in[16];
    const float* abf = (const float*)d_in[17];
    const float* aWb = (const float*)d_in[18];
    const float* aUb = (const float*)d_in[19];
    const float* abb = (const float*)d_in[20];
    const float* mpmw = (const float*)d_in[21];
    const float* fc1W = (const float*)d_in[22];
    const float* fc1b = (const float*)d_in[23];
    const float* fc2W = (const float*)d_in[24];
    const float* fc2b = (const float*)d_in[25];
    float* out = (float*)d_out;

    float* ws = (float*)d_ws;
    float* xw0 = ws; ws += (size_t)4096*512;
    float* xw1 = ws; ws += (size_t)4096*512;
    float* xw2 = ws; ws += (size_t)4096*512;
    float* xw3 = ws; ws += (size_t)4096*512;
    float* pfw = ws; ws += (size_t)4096*128;
    float* pbw = ws; ws += (size_t)4096*128;
    float* qfw = ws; ws += (size_t)4096*128;
    float* qbw = ws; ws += (size_t)4096*128;
    float* cmf = ws; ws += (size_t)64*64*64;
    float* cmb = ws; ws += (size_t)64*64*64;
    float* xcat = ws; ws += (size_t)64*512;
    unsigned short* Xaug = (unsigned short*)ws; ws += (size_t)8192*1152/2;   // bf16 [8192][1152]
    unsigned short* Wfa  = (unsigned short*)ws; ws += (size_t)512*1152/2;
    unsigned short* Wba  = (unsigned short*)ws; ws += (size_t)512*1152/2;
    unsigned short* WihC = (unsigned short*)ws; ws += (size_t)256*192/2;
    unsigned short* WhhC = (unsigned short*)ws; ws += (size_t)256*192/2;

    // 0. char LSTM weight conversions
    k_conv<<<256, 128, 0, stream>>>(cWih, WihC, 64, 64, 1);
    k_conv<<<256, 128, 0, stream>>>(cWhh, WhhC, 64, 64, 1);
    // 1. word embedding gather -> Xaug (split-bf16), zero-pads cols 300..383
    k_embed_word<<<8192, 128, 0, stream>>>(idxA, idxB, wemb, Xaug);
    // 2. char LSTM via MFMA -> Xaug cols 300..363 (split-bf16)
    k_char_mfma<<<256, 256, 0, stream>>>(cidxA, cidxB, cemb, WihC, WhhC, cb, Xaug);
    // 3. ctx weight conversions
    k_conv<<<512, 128, 0, stream>>>(xWf, Wfa, 364, 384, 1);
    k_conv<<<512, 128, 0, stream>>>(xWb, Wba, 364, 384, 1);
    // 4. ctx input projections via MFMA (4 scans: A-f, B-f, A-b, B-b)
    MfArgs cx;
    cx.X = Xaug;
    cx.W[0]=Wfa; cx.W[1]=Wfa; cx.W[2]=Wba; cx.W[3]=Wba;
    cx.bias[0]=xbf; cx.bias[1]=xbf; cx.bias[2]=xbb; cx.bias[3]=xbb;
    cx.out[0]=xw0; cx.out[1]=xw1; cx.out[2]=xw2; cx.out[3]=xw3;
    cx.flip[0]=0; cx.flip[1]=0; cx.flip[2]=1; cx.flip[3]=1;
    cx.rowBase[0]=0; cx.rowBase[1]=4096; cx.rowBase[2]=0; cx.rowBase[3]=4096;
    cx.Kaug = 1152;
    k_xw_mfma<<<dim3(32, 4, 4), 256, 0, stream>>>(cx);
    // 5. ctx recurrences (1024-thread split-K scalar scan, v_pk_fma_f32)
    ScanArgs cs;
    cs.xw[0]=xw0; cs.xw[1]=xw1; cs.xw[2]=xw2; cs.xw[3]=xw3;
    cs.whh[0]=xUf; cs.whh[1]=xUf; cs.whh[2]=xUb; cs.whh[3]=xUb;
    cs.out[0]=pfw; cs.out[1]=qfw; cs.out[2]=pbw; cs.out[3]=qbw;
    cs.flipOut[0]=0; cs.flipOut[1]=0; cs.flipOut[2]=1; cs.flipOut[3]=1;
    cs.writeAll = 1; cs.outStride = 0;
    k_lstm_scan<<<dim3(64, 4), 1024, 0, stream>>>(cs);
    // 6. cosine matrices (p vs q), fw and bw
    k_cos_matrix<<<dim3(64, 2), 256, 0, stream>>>(pfw, pbw, qfw, qbw, cmf, cmb);
    // 7. full / attentive / max-attentive parts -> agg Xaug (split-bf16, stride 480)
    k_full_att<<<dim3(64, 2, 2), 512, 0, stream>>>(pfw, pbw, qfw, qbw, cmf, cmb, mpmw, Xaug);
    // 8. max-pool parts via MFMA -> agg Xaug (row-max -> which=0 rows, col-max -> which=1 rows)
    k_maxpool_mfma<<<dim3(64, 2, 2), 256, 0, stream>>>(pfw, pbw, qfw, qbw, mpmw, Xaug);
    // 9. agg weight conversions (reuse Wfa/Wba; Kaug=480)
    k_conv<<<512, 128, 0, stream>>>(aWf, Wfa, 160, 160, 1);
    k_conv<<<512, 128, 0, stream>>>(aWb, Wba, 160, 160, 1);
    // 10. agg input projections via MFMA
    MfArgs ax;
    ax.X = Xaug;
    ax.W[0]=Wfa; ax.W[1]=Wfa; ax.W[2]=Wba; ax.W[3]=Wba;
    ax.bias[0]=abf; ax.bias[1]=abf; ax.bias[2]=abb; ax.bias[3]=abb;
    ax.out[0]=xw0; ax.out[1]=xw1; ax.out[2]=xw2; ax.out[3]=xw3;
    ax.flip[0]=0; ax.flip[1]=0; ax.flip[2]=1; ax.flip[3]=1;
    ax.rowBase[0]=0; ax.rowBase[1]=4096; ax.rowBase[2]=0; ax.rowBase[3]=4096;
    ax.Kaug = 480;
    k_xw_mfma<<<dim3(32, 4, 4), 256, 0, stream>>>(ax);
    // 11. agg recurrences, final hidden only -> xcat [64][512]
    ScanArgs as;
    as.xw[0]=xw0; as.xw[1]=xw1; as.xw[2]=xw2; as.xw[3]=xw3;
    as.whh[0]=aUf; as.whh[1]=aUf; as.whh[2]=aUb; as.whh[3]=aUb;
    as.out[0]=xcat+0; as.out[1]=xcat+256; as.out[2]=xcat+128; as.out[3]=xcat+384;
    as.flipOut[0]=0; as.flipOut[1]=0; as.flipOut[2]=0; as.flipOut[3]=0;
    as.writeAll = 0; as.outStride = 512;
    k_lstm_scan<<<dim3(64, 4), 1024, 0, stream>>>(as);
    // 12. FC head
    k_fc<<<64, 256, 0, stream>>>(xcat, fc1W, fc1b, fc2W, fc2b, out);
}